// Round 19
// baseline (460.894 us; speedup 1.0000x reference)
//
#include <hip/hip_runtime.h>
#include <hip/hip_fp16.h>

#define TPB 256

typedef _Float16 hv2 __attribute__((ext_vector_type(2)));
typedef _Float16 hv8 __attribute__((ext_vector_type(8)));
typedef _Float16 f16x8 __attribute__((ext_vector_type(8)));
typedef float f32x4v __attribute__((ext_vector_type(4)));

static __device__ __forceinline__ hv2 pkrtz(float a, float b) {
    auto t = __builtin_amdgcn_cvt_pkrtz(a, b);
    return __builtin_bit_cast(hv2, t);
}

template <int CTRL>
static __device__ __forceinline__ float dpp_add(float x) {
    int xi = __builtin_bit_cast(int, x);
    int yi = __builtin_amdgcn_update_dpp(0, xi, CTRL, 0xf, 0xf, true);
    return x + __builtin_bit_cast(float, yi);
}

// butterfly sum over SPAN lanes (SPAN = 2,4,8,16; within a DPP row of 16)
template <int SPAN>
static __device__ __forceinline__ float dpp_reduce(float x) {
    x = dpp_add<0xB1>(x);                              // quad_perm xor1
    if constexpr (SPAN >= 4)  x = dpp_add<0x4E>(x);    // quad_perm xor2
    if constexpr (SPAN >= 8)  x = dpp_add<0x141>(x);   // row_half_mirror == ^7
    if constexpr (SPAN >= 16) x = dpp_add<0x140>(x);   // row_mirror == ^15
    return x;
}

// ---------------- CSR build ----------------

__global__ void k_count(const int* __restrict__ dstA, int* __restrict__ cnt, int E) {
    int e = blockIdx.x * blockDim.x + threadIdx.x;
    if (e >= E) return;
    atomicAdd(&cnt[dstA[e]], 1);
}

// ---- 3-phase exclusive scan of (cnt[i]+1) ----
__global__ void k_scan_part(const int* __restrict__ cnt, int* __restrict__ part,
                            int N, int ept) {
    __shared__ int sm[TPB];
    int tid = threadIdx.x;
    int beg = (blockIdx.x * TPB + tid) * ept;
    int s = 0;
    for (int u = 0; u < ept; ++u) {
        int i = beg + u;
        if (i < N) s += cnt[i] + 1;
    }
    sm[tid] = s;
    __syncthreads();
    for (int st = TPB / 2; st; st >>= 1) {
        if (tid < st) sm[tid] += sm[tid + st];
        __syncthreads();
    }
    if (tid == 0) part[blockIdx.x] = sm[0];
}

__global__ void k_scan_top(int* __restrict__ part, int* __restrict__ rowptr,
                           int nb, int N) {
    int lane = threadIdx.x & 63;
    int orig = (lane < nb) ? part[lane] : 0;
    int v = orig;
    #pragma unroll
    for (int ofs = 1; ofs < 64; ofs <<= 1) {
        int t = __shfl_up(v, ofs);
        if (lane >= ofs) v += t;
    }
    if (lane < nb) part[lane] = v - orig;
    if (lane == 63) rowptr[N] = v;
}

__global__ void k_scan_fin(const int* __restrict__ cnt, const int* __restrict__ part,
                           int* __restrict__ rowptr, int N, int ept) {
    __shared__ int wsum[TPB / 64];
    int tid = threadIdx.x;
    int lane = tid & 63, wid = tid >> 6;
    int beg = (blockIdx.x * TPB + tid) * ept;
    int s = 0;
    for (int u = 0; u < ept; ++u) {
        int i = beg + u;
        if (i < N) s += cnt[i] + 1;
    }
    int v = s;
    #pragma unroll
    for (int ofs = 1; ofs < 64; ofs <<= 1) {
        int t = __shfl_up(v, ofs);
        if (lane >= ofs) v += t;
    }
    if (lane == 63) wsum[wid] = v;
    __syncthreads();
    int woff = 0;
    for (int k = 0; k < wid; ++k) woff += wsum[k];
    int acc = (v - s) + woff + part[blockIdx.x];
    for (int u = 0; u < ept; ++u) {
        int i = beg + u;
        if (i < N) { rowptr[i] = acc; acc += cnt[i] + 1; }
    }
}

// cefs[slot] = (f0, f1, f2, bitcast(src))
__global__ void k_fill(const int* __restrict__ srcA, const int* __restrict__ dstA,
                       const float* __restrict__ ef,
                       const int* __restrict__ rowptr, int* __restrict__ fill,
                       float4* __restrict__ cefs, int E) {
    int e = blockIdx.x * blockDim.x + threadIdx.x;
    if (e >= E) return;
    int d = dstA[e];
    int pos = atomicAdd(&fill[d], 1);
    int slot = rowptr[d] + pos;
    cefs[slot] = make_float4(ef[e * 3 + 0], ef[e * 3 + 1], ef[e * 3 + 2],
                             __int_as_float(srcA[e]));
}

__global__ void k_selfloop(const int* __restrict__ rowptr, const int* __restrict__ cnt,
                           float4* __restrict__ cefs, int N) {
    int i = blockIdx.x * blockDim.x + threadIdx.x;
    if (i >= N) return;
    int b = rowptr[i];
    int c = cnt[i];
    float s0 = 0.f, s1 = 0.f, s2 = 0.f;
    for (int s = b; s < b + c; ++s) {
        float4 q = cefs[s];
        s0 += q.x; s1 += q.y; s2 += q.z;
    }
    float inv = 1.0f / (float)max(c, 1);
    cefs[b + c] = make_float4(s0 * inv, s1 * inv, s2 * inv, __int_as_float(i));
}

// ---------------- layer-0 linear (F=5): simple register-tiled ----------------
template <int F, int HC>
__global__ void k_lin_s(const float* __restrict__ xin,
                        const float* __restrict__ wl, const float* __restrict__ bl,
                        const float* __restrict__ wr, const float* __restrict__ br,
                        __half* __restrict__ xl16, __half* __restrict__ xr16, int N) {
    constexpr int OPT = HC / 16;
    __shared__ float xs[32][F + 1];
    int n0 = blockIdx.x * 32;
    int tid = threadIdx.x;

    for (int idx = tid; idx < 32 * F; idx += TPB) {
        int n = idx / F, k = idx - n * F;
        int gn = n0 + n;
        xs[n][k] = (gn < N) ? xin[(size_t)gn * F + k] : 0.f;
    }
    __syncthreads();

    int og = tid & 31;
    int ng = tid >> 5;
    int o0 = og * OPT;
    bool isL = o0 < HC;
    int col = isL ? o0 : o0 - HC;
    const float* wp = isL ? wl : wr;
    const float* bp = isL ? bl : br;
    __half* outp = isL ? xl16 : xr16;

    float acc[4][OPT];
    #pragma unroll
    for (int j = 0; j < 4; ++j)
        #pragma unroll
        for (int m = 0; m < OPT; ++m) acc[j][m] = 0.f;

    #pragma unroll
    for (int k = 0; k < F; ++k) {
        float wv[OPT];
        #pragma unroll
        for (int m = 0; m < OPT; m += 4)
            *reinterpret_cast<float4*>(&wv[m]) =
                *reinterpret_cast<const float4*>(wp + (size_t)k * HC + col + m);
        #pragma unroll
        for (int j = 0; j < 4; ++j) {
            float xv = xs[ng * 4 + j][k];
            #pragma unroll
            for (int m = 0; m < OPT; ++m) acc[j][m] = fmaf(xv, wv[m], acc[j][m]);
        }
    }

    float bias[OPT];
    #pragma unroll
    for (int m = 0; m < OPT; ++m) bias[m] = bp[col + m];

    #pragma unroll
    for (int j = 0; j < 4; ++j) {
        int node = n0 + ng * 4 + j;
        if (node >= N) continue;
        #pragma unroll
        for (int m = 0; m < OPT; m += 2) {
            __half2 hv = __half2(__float2half(acc[j][m] + bias[m]),
                                 __float2half(acc[j][m + 1] + bias[m + 1]));
            *reinterpret_cast<__half2*>(outp + (size_t)node * HC + col + m) = hv;
        }
    }
}

// ---------------- big linear layers: MFMA fp16 GEMM ----------------
template <int F, int HC>
__global__ void k_lin_mfma(const float* __restrict__ xin,
                           const float* __restrict__ wl, const float* __restrict__ bl,
                           const float* __restrict__ wr, const float* __restrict__ br,
                           __half* __restrict__ xl16, __half* __restrict__ xr16, int N) {
    constexpr int W2 = 2 * HC;
    constexpr int NT = 64;
    constexpr int KC = 32;
    constexpr int CT = W2 / 16;
    constexpr int CTW = CT / 4;
    constexpr int C4 = W2 / 4;
    __shared__ _Float16 xs[NT][F + 8];
    __shared__ _Float16 wsT[W2][KC + 8];

    int n0 = blockIdx.x * NT;
    int tid = threadIdx.x;
    int lane = tid & 63;
    int wv = tid >> 6;
    int lane15 = lane & 15;
    int kb = (lane >> 4) * 8;

    for (int idx = tid * 4; idx < NT * F; idx += TPB * 4) {
        int n = idx / F, k = idx - n * F;
        int gn = n0 + n;
        float4 v = (gn < N) ? *reinterpret_cast<const float4*>(xin + (size_t)gn * F + k)
                            : make_float4(0.f, 0.f, 0.f, 0.f);
        unsigned int lo = __builtin_bit_cast(unsigned int, pkrtz(v.x, v.y));
        unsigned int hi = __builtin_bit_cast(unsigned int, pkrtz(v.z, v.w));
        *reinterpret_cast<uint2*>(&xs[n][k]) = make_uint2(lo, hi);
    }

    f32x4v acc[4][CTW];
    #pragma unroll
    for (int t = 0; t < CTW; ++t) {
        int col = (wv * CTW + t) * 16 + lane15;
        float bv = (col < HC) ? bl[col] : br[col - HC];
        #pragma unroll
        for (int tr = 0; tr < 4; ++tr) acc[tr][t] = (f32x4v){bv, bv, bv, bv};
    }

    for (int kc = 0; kc < F; kc += KC) {
        __syncthreads();
        for (int idx = tid; idx < (KC / 2) * C4; idx += TPB) {
            int k2 = idx / C4;
            int c = (idx - k2 * C4) * 4;
            int k = kc + k2 * 2;
            float4 r0, r1;
            if (c < HC) {
                r0 = *reinterpret_cast<const float4*>(wl + (size_t)k * HC + c);
                r1 = *reinterpret_cast<const float4*>(wl + (size_t)(k + 1) * HC + c);
            } else {
                int cc = c - HC;
                r0 = *reinterpret_cast<const float4*>(wr + (size_t)k * HC + cc);
                r1 = *reinterpret_cast<const float4*>(wr + (size_t)(k + 1) * HC + cc);
            }
            int kk = k2 * 2;
            *reinterpret_cast<unsigned int*>(&wsT[c + 0][kk]) = __builtin_bit_cast(unsigned int, pkrtz(r0.x, r1.x));
            *reinterpret_cast<unsigned int*>(&wsT[c + 1][kk]) = __builtin_bit_cast(unsigned int, pkrtz(r0.y, r1.y));
            *reinterpret_cast<unsigned int*>(&wsT[c + 2][kk]) = __builtin_bit_cast(unsigned int, pkrtz(r0.z, r1.z));
            *reinterpret_cast<unsigned int*>(&wsT[c + 3][kk]) = __builtin_bit_cast(unsigned int, pkrtz(r0.w, r1.w));
        }
        __syncthreads();

        f16x8 a[4];
        #pragma unroll
        for (int tr = 0; tr < 4; ++tr)
            a[tr] = *reinterpret_cast<const f16x8*>(&xs[tr * 16 + lane15][kc + kb]);
        #pragma unroll
        for (int t = 0; t < CTW; ++t) {
            int col = (wv * CTW + t) * 16 + lane15;
            f16x8 bfr = *reinterpret_cast<const f16x8*>(&wsT[col][kb]);
            #pragma unroll
            for (int tr = 0; tr < 4; ++tr)
                acc[tr][t] = __builtin_amdgcn_mfma_f32_16x16x32_f16(a[tr], bfr, acc[tr][t], 0, 0, 0);
        }
    }

    #pragma unroll
    for (int t = 0; t < CTW; ++t) {
        int col = (wv * CTW + t) * 16 + lane15;
        bool isL = col < HC;
        __half* outp = isL ? xl16 : xr16;
        int c = isL ? col : col - HC;
        #pragma unroll
        for (int tr = 0; tr < 4; ++tr) {
            #pragma unroll
            for (int j = 0; j < 4; ++j) {
                int node = n0 + tr * 16 + (lane >> 4) * 4 + j;
                if (node < N) outp[(size_t)node * HC + c] = __float2half(acc[tr][t][j]);
            }
        }
    }
}

// ---------------- fused GATv2 attention + aggregation ----------------
// 8 channels/lane; 2-block rotation software pipeline: next block's 8 gathers
// are in flight across the current block's logit+merge compute.
template <int H, int C>
__global__ void k_fused(const int* __restrict__ rowptr,
                        const float4* __restrict__ cefs,
                        const __half* __restrict__ xl16, const __half* __restrict__ xr16,
                        const float* __restrict__ we, const float* __restrict__ att,
                        const float* __restrict__ cb, float* __restrict__ hout, int N) {
    constexpr int HC = H * C;
    constexpr int PAIRS = HC / 8;   // lanes per node (16 or 8)
    constexpr int NPW = 64 / PAIRS; // nodes per wave (4 or 8)
    constexpr int SPAN = C / 8;     // lanes per head (4 or 2)
    const _Float16* xl = reinterpret_cast<const _Float16*>(xl16);
    int wave = (blockIdx.x * blockDim.x + threadIdx.x) >> 6;
    int lane = threadIdx.x & 63;
    int g = lane / PAIRS;
    int p = lane % PAIRS;
    int node = wave * NPW + g;
    bool act = node < N;

    int o0 = 8 * p;
    hv8 xr8 = {};
    int b = 0, len = 0;
    if (act) {
        xr8 = *reinterpret_cast<const hv8*>(
            reinterpret_cast<const _Float16*>(xr16) + (size_t)node * HC + o0);
        b = rowptr[node];
        len = rowptr[node + 1] - b;
    }
    // we rows packed to f16
    hv8 wa8, wb8, wc8;
    float at[8];
    const float LOG2E = 1.44269504088896340736f;
    #pragma unroll
    for (int m = 0; m < 8; m += 2) {
        hv2 a2 = pkrtz(we[o0 + m], we[o0 + m + 1]);
        hv2 b2 = pkrtz(we[HC + o0 + m], we[HC + o0 + m + 1]);
        hv2 c2 = pkrtz(we[2 * HC + o0 + m], we[2 * HC + o0 + m + 1]);
        wa8[m] = a2[0]; wa8[m + 1] = a2[1];
        wb8[m] = b2[0]; wb8[m + 1] = b2[1];
        wc8[m] = c2[0]; wc8[m + 1] = c2[1];
        at[m] = att[o0 + m] * LOG2E;
        at[m + 1] = att[o0 + m + 1] * LOG2E;
    }
    const _Float16 K02 = (_Float16)0.2f;

    float m_run = -1e30f, den = 0.f;
    float acc[8];
    #pragma unroll
    for (int m = 0; m < 8; ++m) acc[m] = 0.f;

    auto load4 = [&](int k0, float4* q, hv8* x) {
        #pragma unroll
        for (int u = 0; u < 4; ++u) {
            int kk = k0 + u;
            int s = b + ((kk < len) ? kk : 0);
            q[u] = cefs[s];
            x[u] = *reinterpret_cast<const hv8*>(
                xl + (size_t)__float_as_int(q[u].w) * HC + o0);
        }
    };
    auto mergeblk = [&](int k0, const float4* q, const hv8* x) {
        float L[4];
        #pragma unroll
        for (int u = 0; u < 4; ++u) {
            _Float16 qx = (_Float16)q[u].x, qy = (_Float16)q[u].y, qz = (_Float16)q[u].z;
            hv8 t8 = x[u] + (wa8 * qx + (wb8 * qy + (wc8 * qz + xr8)));
            hv8 lr = __builtin_elementwise_max(t8, t8 * K02);  // leaky-relu
            float partial = fmaf((float)lr[0], at[0], fmaf((float)lr[1], at[1],
                            fmaf((float)lr[2], at[2], fmaf((float)lr[3], at[3],
                            fmaf((float)lr[4], at[4], fmaf((float)lr[5], at[5],
                            fmaf((float)lr[6], at[6], (float)lr[7] * at[7])))))));
            partial = dpp_reduce<SPAN>(partial);   // VALU DPP butterfly
            L[u] = (k0 + u < len) ? partial : -1e30f;
        }
        float Lm = fmaxf(fmaxf(L[0], L[1]), fmaxf(L[2], L[3]));
        float nm = fmaxf(m_run, Lm);
        float sc = __builtin_amdgcn_exp2f(m_run - nm);
        float p0 = __builtin_amdgcn_exp2f(L[0] - nm);
        float p1 = __builtin_amdgcn_exp2f(L[1] - nm);
        float p2 = __builtin_amdgcn_exp2f(L[2] - nm);
        float p3 = __builtin_amdgcn_exp2f(L[3] - nm);
        den = den * sc + ((p0 + p1) + (p2 + p3));
        #pragma unroll
        for (int m = 0; m < 8; ++m)
            acc[m] = fmaf(acc[m], sc, fmaf(p0, (float)x[0][m], fmaf(p1, (float)x[1][m],
                          fmaf(p2, (float)x[2][m], p3 * (float)x[3][m]))));
        m_run = nm;
    };

    float4 qA[4], qB[4];
    hv8 xA[4], xB[4];
    load4(0, qA, xA);
    int nk2 = (len + 7) >> 3;  // pairs of 4-edge blocks
    for (int t = 0; t < nk2; ++t) {
        int k0 = t * 8;
        load4(k0 + 4, qB, xB);   // next block's gathers in flight
        mergeblk(k0, qA, xA);
        load4(k0 + 8, qA, xA);   // block after next
        mergeblk(k0 + 4, qB, xB);
    }

    if (act) {
        float inv = 1.0f / den;  // self-loop guarantees den > 0
        float* outp = hout + (size_t)node * HC + o0;
        float4 r0 = make_float4(fmaxf(acc[0] * inv + cb[o0 + 0], 0.f),
                                fmaxf(acc[1] * inv + cb[o0 + 1], 0.f),
                                fmaxf(acc[2] * inv + cb[o0 + 2], 0.f),
                                fmaxf(acc[3] * inv + cb[o0 + 3], 0.f));
        float4 r1 = make_float4(fmaxf(acc[4] * inv + cb[o0 + 4], 0.f),
                                fmaxf(acc[5] * inv + cb[o0 + 5], 0.f),
                                fmaxf(acc[6] * inv + cb[o0 + 6], 0.f),
                                fmaxf(acc[7] * inv + cb[o0 + 7], 0.f));
        *reinterpret_cast<float4*>(outp) = r0;
        *reinterpret_cast<float4*>(outp + 4) = r1;
    }
}

// ---------------- pooling + final linear ----------------
__global__ void k_pool(const float* __restrict__ h, const int* __restrict__ batch,
                       float* __restrict__ psum, int* __restrict__ pcnt, int N) {
    int o = threadIdx.x & 63;
    int j = threadIdx.x >> 6;
    int nb = blockIdx.x * 32;
    float acc = 0.f;
    int gcur = -1, cntacc = 0;
    for (int jj = j; jj < 32; jj += 4) {
        int node = nb + jj;
        if (node >= N) break;
        int g = batch[node];
        if (g != gcur) {
            if (gcur >= 0) {
                atomicAdd(&psum[gcur * 64 + o], acc);
                if (o == 0) atomicAdd(&pcnt[gcur], cntacc);
            }
            gcur = g; acc = 0.f; cntacc = 0;
        }
        acc += h[(size_t)node * 64 + o];
        ++cntacc;
    }
    if (gcur >= 0) {
        atomicAdd(&psum[gcur * 64 + o], acc);
        if (o == 0) atomicAdd(&pcnt[gcur], cntacc);
    }
}

__global__ void k_final(const float* __restrict__ psum, const int* __restrict__ pcnt,
                        const float* __restrict__ wlin, const float* __restrict__ blin,
                        float* __restrict__ out, int G) {
    int t = blockIdx.x * blockDim.x + threadIdx.x;
    if (t >= G * 32) return;
    int g = t / 32, j = t % 32;
    float acc = 0.f;
    for (int k = 0; k < 64; ++k) acc = fmaf(psum[g * 64 + k], wlin[k * 32 + j], acc);
    float inv = 1.0f / (float)max(pcnt[g], 1);
    out[t] = acc * inv + blin[j];
}

// ---------------- host ----------------

extern "C" void kernel_launch(void* const* d_in, const int* in_sizes, int n_in,
                              void* d_out, int out_size, void* d_ws, size_t ws_size,
                              hipStream_t stream) {
    const float* x = (const float*)d_in[0];
    const int* ei = (const int*)d_in[1];
    const float* ef = (const float*)d_in[2];
    const int* batch = (const int*)d_in[3];

    int N = in_sizes[0] / 5;
    int E = in_sizes[1] / 2;
    int G = out_size / 32;
    int Etot = E + N;
    const int* srcA = ei;
    const int* dstA = ei + E;

    char* w = (char*)d_ws;
    size_t off = 0;
    auto A = [&](size_t bytes) -> void* {
        void* p = w + off;
        off = (off + bytes + 255) & ~(size_t)255;
        return p;
    };
    // zero-init region: cnt0, fill, psum, pcnt
    int* cnt0 = (int*)A((size_t)N * 4);
    int* fill = (int*)A((size_t)N * 4);
    float* psum = (float*)A((size_t)G * 64 * 4);
    int* pcnt = (int*)A((size_t)G * 4);
    size_t zbytes = off;
    int* rowptr = (int*)A((size_t)(N + 1) * 4);
    int* part = (int*)A((size_t)64 * 4);
    float4* cefs = (float4*)A((size_t)Etot * 16);
    __half* xl16 = (__half*)A((size_t)N * 128 * 2);
    __half* xr16 = (__half*)A((size_t)N * 128 * 2);
    float* h0 = (float*)A((size_t)N * 128 * 4);
    float* h1 = (float*)A((size_t)N * 128 * 4);

    (void)hipMemsetAsync(d_ws, 0, zbytes, stream);

    dim3 B(TPB);
    int nblkN = (N + TPB - 1) / TPB;
    k_count<<<(E + TPB - 1) / TPB, B, 0, stream>>>(dstA, cnt0, E);

    int ept = (N + 64 * TPB - 1) / (64 * TPB);
    if (ept < 4) ept = 4;
    int nb = (N + ept * TPB - 1) / (ept * TPB);
    k_scan_part<<<nb, B, 0, stream>>>(cnt0, part, N, ept);
    k_scan_top<<<1, 64, 0, stream>>>(part, rowptr, nb, N);
    k_scan_fin<<<nb, B, 0, stream>>>(cnt0, part, rowptr, N, ept);

    k_fill<<<(E + TPB - 1) / TPB, B, 0, stream>>>(srcA, dstA, ef, rowptr, fill, cefs, E);
    k_selfloop<<<nblkN, B, 0, stream>>>(rowptr, cnt0, cefs, N);

    float* houts[4] = {h0, h1, h0, h1};

    int nblk = (N + 31) / 32;
    int nblk64 = (N + 63) / 64;
    const float* hin = x;
    for (int l = 0; l < 4; ++l) {
        const float* wl  = (const float*)d_in[4 + l * 7 + 0];
        const float* bl  = (const float*)d_in[4 + l * 7 + 1];
        const float* wr  = (const float*)d_in[4 + l * 7 + 2];
        const float* br  = (const float*)d_in[4 + l * 7 + 3];
        const float* we  = (const float*)d_in[4 + l * 7 + 4];
        const float* att = (const float*)d_in[4 + l * 7 + 5];
        const float* cb  = (const float*)d_in[4 + l * 7 + 6];
        int H = (l == 3) ? 2 : 4;
        int C = (l == 0) ? 16 : 32;
        int HC = H * C;

        if (l == 0)      k_lin_s<5, 64>      <<<nblk, B, 0, stream>>>(hin, wl, bl, wr, br, xl16, xr16, N);
        else if (l == 1) k_lin_mfma<64, 128> <<<nblk64, B, 0, stream>>>(hin, wl, bl, wr, br, xl16, xr16, N);
        else if (l == 2) k_lin_mfma<128, 128><<<nblk64, B, 0, stream>>>(hin, wl, bl, wr, br, xl16, xr16, N);
        else             k_lin_mfma<128, 64> <<<nblk64, B, 0, stream>>>(hin, wl, bl, wr, br, xl16, xr16, N);

        int npw = 512 / HC;  // nodes per wave at 8 channels/lane
        long long waves = ((long long)N + npw - 1) / npw;
        int blocks = (int)((waves + 3) / 4);
        if (H == 4 && C == 16)
            k_fused<4, 16><<<blocks, B, 0, stream>>>(rowptr, cefs, xl16, xr16,
                                                     we, att, cb, houts[l], N);
        else if (H == 4 && C == 32)
            k_fused<4, 32><<<blocks, B, 0, stream>>>(rowptr, cefs, xl16, xr16,
                                                     we, att, cb, houts[l], N);
        else
            k_fused<2, 32><<<blocks, B, 0, stream>>>(rowptr, cefs, xl16, xr16,
                                                     we, att, cb, houts[l], N);
        hin = houts[l];
    }

    k_pool<<<(N + 31) / 32, B, 0, stream>>>(hin, batch, psum, pcnt, N);
    k_final<<<(G * 32 + TPB - 1) / TPB, B, 0, stream>>>(psum, pcnt,
                                                        (const float*)d_in[32],
                                                        (const float*)d_in[33],
                                                        (float*)d_out, G);
}

// Round 20
// 429.938 us; speedup vs baseline: 1.0720x; 1.0720x over previous
//
#include <hip/hip_runtime.h>
#include <hip/hip_fp16.h>

#define TPB 256

typedef _Float16 hv2 __attribute__((ext_vector_type(2)));
typedef _Float16 hv8 __attribute__((ext_vector_type(8)));
typedef _Float16 f16x8 __attribute__((ext_vector_type(8)));
typedef float f32x4v __attribute__((ext_vector_type(4)));

static __device__ __forceinline__ hv2 pkrtz(float a, float b) {
    auto t = __builtin_amdgcn_cvt_pkrtz(a, b);
    return __builtin_bit_cast(hv2, t);
}

template <int CTRL>
static __device__ __forceinline__ float dpp_add(float x) {
    int xi = __builtin_bit_cast(int, x);
    int yi = __builtin_amdgcn_update_dpp(0, xi, CTRL, 0xf, 0xf, true);
    return x + __builtin_bit_cast(float, yi);
}

// butterfly sum over SPAN lanes (SPAN = 2,4,8,16; within a DPP row of 16)
template <int SPAN>
static __device__ __forceinline__ float dpp_reduce(float x) {
    x = dpp_add<0xB1>(x);                              // quad_perm xor1
    if constexpr (SPAN >= 4)  x = dpp_add<0x4E>(x);    // quad_perm xor2
    if constexpr (SPAN >= 8)  x = dpp_add<0x141>(x);   // row_half_mirror == ^7
    if constexpr (SPAN >= 16) x = dpp_add<0x140>(x);   // row_mirror == ^15
    return x;
}

// ---------------- CSR build ----------------

__global__ void k_count(const int* __restrict__ dstA, int* __restrict__ cnt, int E) {
    int e = blockIdx.x * blockDim.x + threadIdx.x;
    if (e >= E) return;
    atomicAdd(&cnt[dstA[e]], 1);
}

// ---- 3-phase exclusive scan of (cnt[i]+1) ----
__global__ void k_scan_part(const int* __restrict__ cnt, int* __restrict__ part,
                            int N, int ept) {
    __shared__ int sm[TPB];
    int tid = threadIdx.x;
    int beg = (blockIdx.x * TPB + tid) * ept;
    int s = 0;
    for (int u = 0; u < ept; ++u) {
        int i = beg + u;
        if (i < N) s += cnt[i] + 1;
    }
    sm[tid] = s;
    __syncthreads();
    for (int st = TPB / 2; st; st >>= 1) {
        if (tid < st) sm[tid] += sm[tid + st];
        __syncthreads();
    }
    if (tid == 0) part[blockIdx.x] = sm[0];
}

__global__ void k_scan_top(int* __restrict__ part, int* __restrict__ rowptr,
                           int nb, int N) {
    int lane = threadIdx.x & 63;
    int orig = (lane < nb) ? part[lane] : 0;
    int v = orig;
    #pragma unroll
    for (int ofs = 1; ofs < 64; ofs <<= 1) {
        int t = __shfl_up(v, ofs);
        if (lane >= ofs) v += t;
    }
    if (lane < nb) part[lane] = v - orig;
    if (lane == 63) rowptr[N] = v;
}

__global__ void k_scan_fin(const int* __restrict__ cnt, const int* __restrict__ part,
                           int* __restrict__ rowptr, int N, int ept) {
    __shared__ int wsum[TPB / 64];
    int tid = threadIdx.x;
    int lane = tid & 63, wid = tid >> 6;
    int beg = (blockIdx.x * TPB + tid) * ept;
    int s = 0;
    for (int u = 0; u < ept; ++u) {
        int i = beg + u;
        if (i < N) s += cnt[i] + 1;
    }
    int v = s;
    #pragma unroll
    for (int ofs = 1; ofs < 64; ofs <<= 1) {
        int t = __shfl_up(v, ofs);
        if (lane >= ofs) v += t;
    }
    if (lane == 63) wsum[wid] = v;
    __syncthreads();
    int woff = 0;
    for (int k = 0; k < wid; ++k) woff += wsum[k];
    int acc = (v - s) + woff + part[blockIdx.x];
    for (int u = 0; u < ept; ++u) {
        int i = beg + u;
        if (i < N) { rowptr[i] = acc; acc += cnt[i] + 1; }
    }
}

// pass 1: slot assignment; 4B scatter of edge id into eid[slot]
__global__ void k_slot(const int* __restrict__ dstA, const int* __restrict__ rowptr,
                       int* __restrict__ fill, int* __restrict__ eid, int E) {
    int e = blockIdx.x * blockDim.x + threadIdx.x;
    if (e >= E) return;
    int d = dstA[e];
    int pos = atomicAdd(&fill[d], 1);
    eid[rowptr[d] + pos] = e;
}

// pass 2: slot-major gather of edge payload; coalesced cefs write
__global__ void k_gat(const int* __restrict__ eid, const int* __restrict__ srcA,
                      const float* __restrict__ ef, float4* __restrict__ cefs,
                      int Etot) {
    int s = blockIdx.x * blockDim.x + threadIdx.x;
    if (s >= Etot) return;
    int e = eid[s];
    if (e < 0) return;  // self-loop slot, filled by k_selfloop
    cefs[s] = make_float4(ef[e * 3 + 0], ef[e * 3 + 1], ef[e * 3 + 2],
                          __int_as_float(srcA[e]));
}

__global__ void k_selfloop(const int* __restrict__ rowptr, const int* __restrict__ cnt,
                           float4* __restrict__ cefs, int N) {
    int i = blockIdx.x * blockDim.x + threadIdx.x;
    if (i >= N) return;
    int b = rowptr[i];
    int c = cnt[i];
    float s0 = 0.f, s1 = 0.f, s2 = 0.f;
    for (int s = b; s < b + c; ++s) {
        float4 q = cefs[s];
        s0 += q.x; s1 += q.y; s2 += q.z;
    }
    float inv = 1.0f / (float)max(c, 1);
    cefs[b + c] = make_float4(s0 * inv, s1 * inv, s2 * inv, __int_as_float(i));
}

// ---------------- layer-0 linear (F=5): simple register-tiled ----------------
template <int F, int HC>
__global__ void k_lin_s(const float* __restrict__ xin,
                        const float* __restrict__ wl, const float* __restrict__ bl,
                        const float* __restrict__ wr, const float* __restrict__ br,
                        __half* __restrict__ xl16, __half* __restrict__ xr16, int N) {
    constexpr int OPT = HC / 16;
    __shared__ float xs[32][F + 1];
    int n0 = blockIdx.x * 32;
    int tid = threadIdx.x;

    for (int idx = tid; idx < 32 * F; idx += TPB) {
        int n = idx / F, k = idx - n * F;
        int gn = n0 + n;
        xs[n][k] = (gn < N) ? xin[(size_t)gn * F + k] : 0.f;
    }
    __syncthreads();

    int og = tid & 31;
    int ng = tid >> 5;
    int o0 = og * OPT;
    bool isL = o0 < HC;
    int col = isL ? o0 : o0 - HC;
    const float* wp = isL ? wl : wr;
    const float* bp = isL ? bl : br;
    __half* outp = isL ? xl16 : xr16;

    float acc[4][OPT];
    #pragma unroll
    for (int j = 0; j < 4; ++j)
        #pragma unroll
        for (int m = 0; m < OPT; ++m) acc[j][m] = 0.f;

    #pragma unroll
    for (int k = 0; k < F; ++k) {
        float wv[OPT];
        #pragma unroll
        for (int m = 0; m < OPT; m += 4)
            *reinterpret_cast<float4*>(&wv[m]) =
                *reinterpret_cast<const float4*>(wp + (size_t)k * HC + col + m);
        #pragma unroll
        for (int j = 0; j < 4; ++j) {
            float xv = xs[ng * 4 + j][k];
            #pragma unroll
            for (int m = 0; m < OPT; ++m) acc[j][m] = fmaf(xv, wv[m], acc[j][m]);
        }
    }

    float bias[OPT];
    #pragma unroll
    for (int m = 0; m < OPT; ++m) bias[m] = bp[col + m];

    #pragma unroll
    for (int j = 0; j < 4; ++j) {
        int node = n0 + ng * 4 + j;
        if (node >= N) continue;
        #pragma unroll
        for (int m = 0; m < OPT; m += 2) {
            __half2 hv = __half2(__float2half(acc[j][m] + bias[m]),
                                 __float2half(acc[j][m + 1] + bias[m + 1]));
            *reinterpret_cast<__half2*>(outp + (size_t)node * HC + col + m) = hv;
        }
    }
}

// ---------------- big linear layers: MFMA fp16 GEMM ----------------
template <int F, int HC>
__global__ void k_lin_mfma(const float* __restrict__ xin,
                           const float* __restrict__ wl, const float* __restrict__ bl,
                           const float* __restrict__ wr, const float* __restrict__ br,
                           __half* __restrict__ xl16, __half* __restrict__ xr16, int N) {
    constexpr int W2 = 2 * HC;
    constexpr int NT = 64;
    constexpr int KC = 32;
    constexpr int CT = W2 / 16;
    constexpr int CTW = CT / 4;
    constexpr int C4 = W2 / 4;
    __shared__ _Float16 xs[NT][F + 8];
    __shared__ _Float16 wsT[W2][KC + 8];

    int n0 = blockIdx.x * NT;
    int tid = threadIdx.x;
    int lane = tid & 63;
    int wv = tid >> 6;
    int lane15 = lane & 15;
    int kb = (lane >> 4) * 8;

    for (int idx = tid * 4; idx < NT * F; idx += TPB * 4) {
        int n = idx / F, k = idx - n * F;
        int gn = n0 + n;
        float4 v = (gn < N) ? *reinterpret_cast<const float4*>(xin + (size_t)gn * F + k)
                            : make_float4(0.f, 0.f, 0.f, 0.f);
        unsigned int lo = __builtin_bit_cast(unsigned int, pkrtz(v.x, v.y));
        unsigned int hi = __builtin_bit_cast(unsigned int, pkrtz(v.z, v.w));
        *reinterpret_cast<uint2*>(&xs[n][k]) = make_uint2(lo, hi);
    }

    f32x4v acc[4][CTW];
    #pragma unroll
    for (int t = 0; t < CTW; ++t) {
        int col = (wv * CTW + t) * 16 + lane15;
        float bv = (col < HC) ? bl[col] : br[col - HC];
        #pragma unroll
        for (int tr = 0; tr < 4; ++tr) acc[tr][t] = (f32x4v){bv, bv, bv, bv};
    }

    for (int kc = 0; kc < F; kc += KC) {
        __syncthreads();
        for (int idx = tid; idx < (KC / 2) * C4; idx += TPB) {
            int k2 = idx / C4;
            int c = (idx - k2 * C4) * 4;
            int k = kc + k2 * 2;
            float4 r0, r1;
            if (c < HC) {
                r0 = *reinterpret_cast<const float4*>(wl + (size_t)k * HC + c);
                r1 = *reinterpret_cast<const float4*>(wl + (size_t)(k + 1) * HC + c);
            } else {
                int cc = c - HC;
                r0 = *reinterpret_cast<const float4*>(wr + (size_t)k * HC + cc);
                r1 = *reinterpret_cast<const float4*>(wr + (size_t)(k + 1) * HC + cc);
            }
            int kk = k2 * 2;
            *reinterpret_cast<unsigned int*>(&wsT[c + 0][kk]) = __builtin_bit_cast(unsigned int, pkrtz(r0.x, r1.x));
            *reinterpret_cast<unsigned int*>(&wsT[c + 1][kk]) = __builtin_bit_cast(unsigned int, pkrtz(r0.y, r1.y));
            *reinterpret_cast<unsigned int*>(&wsT[c + 2][kk]) = __builtin_bit_cast(unsigned int, pkrtz(r0.z, r1.z));
            *reinterpret_cast<unsigned int*>(&wsT[c + 3][kk]) = __builtin_bit_cast(unsigned int, pkrtz(r0.w, r1.w));
        }
        __syncthreads();

        f16x8 a[4];
        #pragma unroll
        for (int tr = 0; tr < 4; ++tr)
            a[tr] = *reinterpret_cast<const f16x8*>(&xs[tr * 16 + lane15][kc + kb]);
        #pragma unroll
        for (int t = 0; t < CTW; ++t) {
            int col = (wv * CTW + t) * 16 + lane15;
            f16x8 bfr = *reinterpret_cast<const f16x8*>(&wsT[col][kb]);
            #pragma unroll
            for (int tr = 0; tr < 4; ++tr)
                acc[tr][t] = __builtin_amdgcn_mfma_f32_16x16x32_f16(a[tr], bfr, acc[tr][t], 0, 0, 0);
        }
    }

    #pragma unroll
    for (int t = 0; t < CTW; ++t) {
        int col = (wv * CTW + t) * 16 + lane15;
        bool isL = col < HC;
        __half* outp = isL ? xl16 : xr16;
        int c = isL ? col : col - HC;
        #pragma unroll
        for (int tr = 0; tr < 4; ++tr) {
            #pragma unroll
            for (int j = 0; j < 4; ++j) {
                int node = n0 + tr * 16 + (lane >> 4) * 4 + j;
                if (node < N) outp[(size_t)node * HC + c] = __float2half(acc[tr][t][j]);
            }
        }
    }
}

// ---------------- fused GATv2 attention + aggregation ----------------
// 8 channels/lane (R16-proven form): wave carries NPW=512/HC nodes.
template <int H, int C>
__global__ void k_fused(const int* __restrict__ rowptr,
                        const float4* __restrict__ cefs,
                        const __half* __restrict__ xl16, const __half* __restrict__ xr16,
                        const float* __restrict__ we, const float* __restrict__ att,
                        const float* __restrict__ cb, float* __restrict__ hout, int N) {
    constexpr int HC = H * C;
    constexpr int PAIRS = HC / 8;   // lanes per node (16 or 8)
    constexpr int NPW = 64 / PAIRS; // nodes per wave (4 or 8)
    constexpr int SPAN = C / 8;     // lanes per head (4 or 2)
    const _Float16* xl = reinterpret_cast<const _Float16*>(xl16);
    int wave = (blockIdx.x * blockDim.x + threadIdx.x) >> 6;
    int lane = threadIdx.x & 63;
    int g = lane / PAIRS;
    int p = lane % PAIRS;
    int node = wave * NPW + g;
    bool act = node < N;

    int o0 = 8 * p;
    hv8 xr8 = {};
    int b = 0, len = 0;
    if (act) {
        xr8 = *reinterpret_cast<const hv8*>(
            reinterpret_cast<const _Float16*>(xr16) + (size_t)node * HC + o0);
        b = rowptr[node];
        len = rowptr[node + 1] - b;
    }
    // we rows packed to f16
    hv8 wa8, wb8, wc8;
    float at[8];
    const float LOG2E = 1.44269504088896340736f;
    #pragma unroll
    for (int m = 0; m < 8; m += 2) {
        hv2 a2 = pkrtz(we[o0 + m], we[o0 + m + 1]);
        hv2 b2 = pkrtz(we[HC + o0 + m], we[HC + o0 + m + 1]);
        hv2 c2 = pkrtz(we[2 * HC + o0 + m], we[2 * HC + o0 + m + 1]);
        wa8[m] = a2[0]; wa8[m + 1] = a2[1];
        wb8[m] = b2[0]; wb8[m + 1] = b2[1];
        wc8[m] = c2[0]; wc8[m + 1] = c2[1];
        at[m] = att[o0 + m] * LOG2E;
        at[m + 1] = att[o0 + m + 1] * LOG2E;
    }
    const _Float16 K02 = (_Float16)0.2f;

    float m_run = -1e30f, den = 0.f;
    float acc[8];
    #pragma unroll
    for (int m = 0; m < 8; ++m) acc[m] = 0.f;

    int nk = (len + 3) >> 2;
    for (int kb = 0; kb < nk; ++kb) {
        int k0 = kb * 4;
        float L[4];
        hv8 xh[4];
        #pragma unroll
        for (int u = 0; u < 4; ++u) {
            int kk = k0 + u;
            bool v = kk < len;
            int s = b + (v ? kk : 0);
            float4 q = cefs[s];
            int src = __float_as_int(q.w);
            hv8 x8 = *reinterpret_cast<const hv8*>(xl + (size_t)src * HC + o0);
            _Float16 qx = (_Float16)q.x, qy = (_Float16)q.y, qz = (_Float16)q.z;
            hv8 t8 = x8 + (wa8 * qx + (wb8 * qy + (wc8 * qz + xr8)));
            hv8 lr = __builtin_elementwise_max(t8, t8 * K02);  // leaky-relu
            float partial = fmaf((float)lr[0], at[0], fmaf((float)lr[1], at[1],
                            fmaf((float)lr[2], at[2], fmaf((float)lr[3], at[3],
                            fmaf((float)lr[4], at[4], fmaf((float)lr[5], at[5],
                            fmaf((float)lr[6], at[6], (float)lr[7] * at[7])))))));
            partial = dpp_reduce<SPAN>(partial);   // VALU DPP butterfly
            L[u] = v ? partial : -1e30f;
            xh[u] = x8;
        }
        float Lm = fmaxf(fmaxf(L[0], L[1]), fmaxf(L[2], L[3]));
        float nm = fmaxf(m_run, Lm);
        float sc = __builtin_amdgcn_exp2f(m_run - nm);
        float p0 = __builtin_amdgcn_exp2f(L[0] - nm);
        float p1 = __builtin_amdgcn_exp2f(L[1] - nm);
        float p2 = __builtin_amdgcn_exp2f(L[2] - nm);
        float p3 = __builtin_amdgcn_exp2f(L[3] - nm);
        den = den * sc + ((p0 + p1) + (p2 + p3));
        #pragma unroll
        for (int m = 0; m < 8; ++m)
            acc[m] = fmaf(acc[m], sc, fmaf(p0, (float)xh[0][m], fmaf(p1, (float)xh[1][m],
                          fmaf(p2, (float)xh[2][m], p3 * (float)xh[3][m]))));
        m_run = nm;
    }

    if (act) {
        float inv = 1.0f / den;  // self-loop guarantees den > 0
        float* outp = hout + (size_t)node * HC + o0;
        float4 r0 = make_float4(fmaxf(acc[0] * inv + cb[o0 + 0], 0.f),
                                fmaxf(acc[1] * inv + cb[o0 + 1], 0.f),
                                fmaxf(acc[2] * inv + cb[o0 + 2], 0.f),
                                fmaxf(acc[3] * inv + cb[o0 + 3], 0.f));
        float4 r1 = make_float4(fmaxf(acc[4] * inv + cb[o0 + 4], 0.f),
                                fmaxf(acc[5] * inv + cb[o0 + 5], 0.f),
                                fmaxf(acc[6] * inv + cb[o0 + 6], 0.f),
                                fmaxf(acc[7] * inv + cb[o0 + 7], 0.f));
        *reinterpret_cast<float4*>(outp) = r0;
        *reinterpret_cast<float4*>(outp + 4) = r1;
    }
}

// ---------------- pooling + final linear ----------------
__global__ void k_pool(const float* __restrict__ h, const int* __restrict__ batch,
                       float* __restrict__ psum, int* __restrict__ pcnt, int N) {
    int o = threadIdx.x & 63;
    int j = threadIdx.x >> 6;
    int nb = blockIdx.x * 32;
    float acc = 0.f;
    int gcur = -1, cntacc = 0;
    for (int jj = j; jj < 32; jj += 4) {
        int node = nb + jj;
        if (node >= N) break;
        int g = batch[node];
        if (g != gcur) {
            if (gcur >= 0) {
                atomicAdd(&psum[gcur * 64 + o], acc);
                if (o == 0) atomicAdd(&pcnt[gcur], cntacc);
            }
            gcur = g; acc = 0.f; cntacc = 0;
        }
        acc += h[(size_t)node * 64 + o];
        ++cntacc;
    }
    if (gcur >= 0) {
        atomicAdd(&psum[gcur * 64 + o], acc);
        if (o == 0) atomicAdd(&pcnt[gcur], cntacc);
    }
}

__global__ void k_final(const float* __restrict__ psum, const int* __restrict__ pcnt,
                        const float* __restrict__ wlin, const float* __restrict__ blin,
                        float* __restrict__ out, int G) {
    int t = blockIdx.x * blockDim.x + threadIdx.x;
    if (t >= G * 32) return;
    int g = t / 32, j = t % 32;
    float acc = 0.f;
    for (int k = 0; k < 64; ++k) acc = fmaf(psum[g * 64 + k], wlin[k * 32 + j], acc);
    float inv = 1.0f / (float)max(pcnt[g], 1);
    out[t] = acc * inv + blin[j];
}

// ---------------- host ----------------

extern "C" void kernel_launch(void* const* d_in, const int* in_sizes, int n_in,
                              void* d_out, int out_size, void* d_ws, size_t ws_size,
                              hipStream_t stream) {
    const float* x = (const float*)d_in[0];
    const int* ei = (const int*)d_in[1];
    const float* ef = (const float*)d_in[2];
    const int* batch = (const int*)d_in[3];

    int N = in_sizes[0] / 5;
    int E = in_sizes[1] / 2;
    int G = out_size / 32;
    int Etot = E + N;
    const int* srcA = ei;
    const int* dstA = ei + E;

    char* w = (char*)d_ws;
    size_t off = 0;
    auto A = [&](size_t bytes) -> void* {
        void* p = w + off;
        off = (off + bytes + 255) & ~(size_t)255;
        return p;
    };
    // zero-init region: cnt0, fill, psum, pcnt
    int* cnt0 = (int*)A((size_t)N * 4);
    int* fill = (int*)A((size_t)N * 4);
    float* psum = (float*)A((size_t)G * 64 * 4);
    int* pcnt = (int*)A((size_t)G * 4);
    size_t zbytes = off;
    int* rowptr = (int*)A((size_t)(N + 1) * 4);
    int* part = (int*)A((size_t)64 * 4);
    int* eid = (int*)A((size_t)Etot * 4);
    float4* cefs = (float4*)A((size_t)Etot * 16);
    __half* xl16 = (__half*)A((size_t)N * 128 * 2);
    __half* xr16 = (__half*)A((size_t)N * 128 * 2);
    float* h0 = (float*)A((size_t)N * 128 * 4);
    float* h1 = (float*)A((size_t)N * 128 * 4);

    (void)hipMemsetAsync(d_ws, 0, zbytes, stream);
    (void)hipMemsetAsync(eid, 0xFF, (size_t)Etot * 4, stream);  // eid = -1

    dim3 B(TPB);
    int nblkN = (N + TPB - 1) / TPB;
    k_count<<<(E + TPB - 1) / TPB, B, 0, stream>>>(dstA, cnt0, E);

    int ept = (N + 64 * TPB - 1) / (64 * TPB);
    if (ept < 4) ept = 4;
    int nb = (N + ept * TPB - 1) / (ept * TPB);
    k_scan_part<<<nb, B, 0, stream>>>(cnt0, part, N, ept);
    k_scan_top<<<1, 64, 0, stream>>>(part, rowptr, nb, N);
    k_scan_fin<<<nb, B, 0, stream>>>(cnt0, part, rowptr, N, ept);

    k_slot<<<(E + TPB - 1) / TPB, B, 0, stream>>>(dstA, rowptr, fill, eid, E);
    k_gat<<<(Etot + TPB - 1) / TPB, B, 0, stream>>>(eid, srcA, ef, cefs, Etot);
    k_selfloop<<<nblkN, B, 0, stream>>>(rowptr, cnt0, cefs, N);

    float* houts[4] = {h0, h1, h0, h1};

    int nblk = (N + 31) / 32;
    int nblk64 = (N + 63) / 64;
    const float* hin = x;
    for (int l = 0; l < 4; ++l) {
        const float* wl  = (const float*)d_in[4 + l * 7 + 0];
        const float* bl  = (const float*)d_in[4 + l * 7 + 1];
        const float* wr  = (const float*)d_in[4 + l * 7 + 2];
        const float* br  = (const float*)d_in[4 + l * 7 + 3];
        const float* we  = (const float*)d_in[4 + l * 7 + 4];
        const float* att = (const float*)d_in[4 + l * 7 + 5];
        const float* cb  = (const float*)d_in[4 + l * 7 + 6];
        int H = (l == 3) ? 2 : 4;
        int C = (l == 0) ? 16 : 32;
        int HC = H * C;

        if (l == 0)      k_lin_s<5, 64>      <<<nblk, B, 0, stream>>>(hin, wl, bl, wr, br, xl16, xr16, N);
        else if (l == 1) k_lin_mfma<64, 128> <<<nblk64, B, 0, stream>>>(hin, wl, bl, wr, br, xl16, xr16, N);
        else if (l == 2) k_lin_mfma<128, 128><<<nblk64, B, 0, stream>>>(hin, wl, bl, wr, br, xl16, xr16, N);
        else             k_lin_mfma<128, 64> <<<nblk64, B, 0, stream>>>(hin, wl, bl, wr, br, xl16, xr16, N);

        int npw = 512 / HC;  // nodes per wave at 8 channels/lane
        long long waves = ((long long)N + npw - 1) / npw;
        int blocks = (int)((waves + 3) / 4);
        if (H == 4 && C == 16)
            k_fused<4, 16><<<blocks, B, 0, stream>>>(rowptr, cefs, xl16, xr16,
                                                     we, att, cb, houts[l], N);
        else if (H == 4 && C == 32)
            k_fused<4, 32><<<blocks, B, 0, stream>>>(rowptr, cefs, xl16, xr16,
                                                     we, att, cb, houts[l], N);
        else
            k_fused<2, 32><<<blocks, B, 0, stream>>>(rowptr, cefs, xl16, xr16,
                                                     we, att, cb, houts[l], N);
        hin = houts[l];
    }

    k_pool<<<(N + 31) / 32, B, 0, stream>>>(hin, batch, psum, pcnt, N);
    k_final<<<(G * 32 + TPB - 1) / TPB, B, 0, stream>>>(psum, pcnt,
                                                        (const float*)d_in[32],
                                                        (const float*)d_in[33],
                                                        (float*)d_out, G);
}

// Round 21
// 359.174 us; speedup vs baseline: 1.2832x; 1.1970x over previous
//
#include <hip/hip_runtime.h>
#include <hip/hip_fp16.h>

#define TPB 256

typedef _Float16 hv2 __attribute__((ext_vector_type(2)));
typedef _Float16 hv8 __attribute__((ext_vector_type(8)));
typedef _Float16 f16x8 __attribute__((ext_vector_type(8)));
typedef float f32x4v __attribute__((ext_vector_type(4)));

static __device__ __forceinline__ hv2 pkrtz(float a, float b) {
    auto t = __builtin_amdgcn_cvt_pkrtz(a, b);
    return __builtin_bit_cast(hv2, t);
}

template <int CTRL>
static __device__ __forceinline__ float dpp_add(float x) {
    int xi = __builtin_bit_cast(int, x);
    int yi = __builtin_amdgcn_update_dpp(0, xi, CTRL, 0xf, 0xf, true);
    return x + __builtin_bit_cast(float, yi);
}

// butterfly sum over SPAN lanes (SPAN = 2,4,8,16; within a DPP row of 16)
template <int SPAN>
static __device__ __forceinline__ float dpp_reduce(float x) {
    x = dpp_add<0xB1>(x);                              // quad_perm xor1
    if constexpr (SPAN >= 4)  x = dpp_add<0x4E>(x);    // quad_perm xor2
    if constexpr (SPAN >= 8)  x = dpp_add<0x141>(x);   // row_half_mirror == ^7
    if constexpr (SPAN >= 16) x = dpp_add<0x140>(x);   // row_mirror == ^15
    return x;
}

// ---------------- CSR build ----------------

// count + within-row position in one pass (epos write is coalesced)
__global__ void k_count2(const int* __restrict__ dstA, int* __restrict__ cnt,
                         int* __restrict__ epos, int E) {
    int e = blockIdx.x * blockDim.x + threadIdx.x;
    if (e >= E) return;
    epos[e] = atomicAdd(&cnt[dstA[e]], 1);
}

// ---- 3-phase exclusive scan of (cnt[i]+1) ----
__global__ void k_scan_part(const int* __restrict__ cnt, int* __restrict__ part,
                            int N, int ept) {
    __shared__ int sm[TPB];
    int tid = threadIdx.x;
    int beg = (blockIdx.x * TPB + tid) * ept;
    int s = 0;
    for (int u = 0; u < ept; ++u) {
        int i = beg + u;
        if (i < N) s += cnt[i] + 1;
    }
    sm[tid] = s;
    __syncthreads();
    for (int st = TPB / 2; st; st >>= 1) {
        if (tid < st) sm[tid] += sm[tid + st];
        __syncthreads();
    }
    if (tid == 0) part[blockIdx.x] = sm[0];
}

__global__ void k_scan_top(int* __restrict__ part, int* __restrict__ rowptr,
                           int nb, int N) {
    int lane = threadIdx.x & 63;
    int orig = (lane < nb) ? part[lane] : 0;
    int v = orig;
    #pragma unroll
    for (int ofs = 1; ofs < 64; ofs <<= 1) {
        int t = __shfl_up(v, ofs);
        if (lane >= ofs) v += t;
    }
    if (lane < nb) part[lane] = v - orig;
    if (lane == 63) rowptr[N] = v;
}

__global__ void k_scan_fin(const int* __restrict__ cnt, const int* __restrict__ part,
                           int* __restrict__ rowptr, int N, int ept) {
    __shared__ int wsum[TPB / 64];
    int tid = threadIdx.x;
    int lane = tid & 63, wid = tid >> 6;
    int beg = (blockIdx.x * TPB + tid) * ept;
    int s = 0;
    for (int u = 0; u < ept; ++u) {
        int i = beg + u;
        if (i < N) s += cnt[i] + 1;
    }
    int v = s;
    #pragma unroll
    for (int ofs = 1; ofs < 64; ofs <<= 1) {
        int t = __shfl_up(v, ofs);
        if (lane >= ofs) v += t;
    }
    if (lane == 63) wsum[wid] = v;
    __syncthreads();
    int woff = 0;
    for (int k = 0; k < wid; ++k) woff += wsum[k];
    int acc = (v - s) + woff + part[blockIdx.x];
    for (int u = 0; u < ept; ++u) {
        int i = beg + u;
        if (i < N) { rowptr[i] = acc; acc += cnt[i] + 1; }
    }
}

// edge scatter: slot = rowptr[dst] + epos (no atomic)
__global__ void k_fill2(const int* __restrict__ srcA, const int* __restrict__ dstA,
                        const int* __restrict__ epos, const float* __restrict__ ef,
                        const int* __restrict__ rowptr, float4* __restrict__ cefs, int E) {
    int e = blockIdx.x * blockDim.x + threadIdx.x;
    if (e >= E) return;
    int d = dstA[e];
    int slot = rowptr[d] + epos[e];
    cefs[slot] = make_float4(ef[e * 3 + 0], ef[e * 3 + 1], ef[e * 3 + 2],
                             __int_as_float(srcA[e]));
}

__global__ void k_selfloop(const int* __restrict__ rowptr, const int* __restrict__ cnt,
                           float4* __restrict__ cefs, int N) {
    int i = blockIdx.x * blockDim.x + threadIdx.x;
    if (i >= N) return;
    int b = rowptr[i];
    int c = cnt[i];
    float s0 = 0.f, s1 = 0.f, s2 = 0.f;
    for (int s = b; s < b + c; ++s) {
        float4 q = cefs[s];
        s0 += q.x; s1 += q.y; s2 += q.z;
    }
    float inv = 1.0f / (float)max(c, 1);
    cefs[b + c] = make_float4(s0 * inv, s1 * inv, s2 * inv, __int_as_float(i));
}

// ---------------- layer-0 linear (F=5): simple register-tiled ----------------
template <int F, int HC>
__global__ void k_lin_s(const float* __restrict__ xin,
                        const float* __restrict__ wl, const float* __restrict__ bl,
                        const float* __restrict__ wr, const float* __restrict__ br,
                        __half* __restrict__ xl16, __half* __restrict__ xr16, int N) {
    constexpr int OPT = HC / 16;
    __shared__ float xs[32][F + 1];
    int n0 = blockIdx.x * 32;
    int tid = threadIdx.x;

    for (int idx = tid; idx < 32 * F; idx += TPB) {
        int n = idx / F, k = idx - n * F;
        int gn = n0 + n;
        xs[n][k] = (gn < N) ? xin[(size_t)gn * F + k] : 0.f;
    }
    __syncthreads();

    int og = tid & 31;
    int ng = tid >> 5;
    int o0 = og * OPT;
    bool isL = o0 < HC;
    int col = isL ? o0 : o0 - HC;
    const float* wp = isL ? wl : wr;
    const float* bp = isL ? bl : br;
    __half* outp = isL ? xl16 : xr16;

    float acc[4][OPT];
    #pragma unroll
    for (int j = 0; j < 4; ++j)
        #pragma unroll
        for (int m = 0; m < OPT; ++m) acc[j][m] = 0.f;

    #pragma unroll
    for (int k = 0; k < F; ++k) {
        float wv[OPT];
        #pragma unroll
        for (int m = 0; m < OPT; m += 4)
            *reinterpret_cast<float4*>(&wv[m]) =
                *reinterpret_cast<const float4*>(wp + (size_t)k * HC + col + m);
        #pragma unroll
        for (int j = 0; j < 4; ++j) {
            float xv = xs[ng * 4 + j][k];
            #pragma unroll
            for (int m = 0; m < OPT; ++m) acc[j][m] = fmaf(xv, wv[m], acc[j][m]);
        }
    }

    float bias[OPT];
    #pragma unroll
    for (int m = 0; m < OPT; ++m) bias[m] = bp[col + m];

    #pragma unroll
    for (int j = 0; j < 4; ++j) {
        int node = n0 + ng * 4 + j;
        if (node >= N) continue;
        #pragma unroll
        for (int m = 0; m < OPT; m += 2) {
            __half2 hv = __half2(__float2half(acc[j][m] + bias[m]),
                                 __float2half(acc[j][m + 1] + bias[m + 1]));
            *reinterpret_cast<__half2*>(outp + (size_t)node * HC + col + m) = hv;
        }
    }
}

// ---------------- big linear layers: MFMA fp16 GEMM ----------------
template <int F, int HC>
__global__ void k_lin_mfma(const float* __restrict__ xin,
                           const float* __restrict__ wl, const float* __restrict__ bl,
                           const float* __restrict__ wr, const float* __restrict__ br,
                           __half* __restrict__ xl16, __half* __restrict__ xr16, int N) {
    constexpr int W2 = 2 * HC;
    constexpr int NT = 64;
    constexpr int KC = 32;
    constexpr int CT = W2 / 16;
    constexpr int CTW = CT / 4;
    constexpr int C4 = W2 / 4;
    __shared__ _Float16 xs[NT][F + 8];
    __shared__ _Float16 wsT[W2][KC + 8];

    int n0 = blockIdx.x * NT;
    int tid = threadIdx.x;
    int lane = tid & 63;
    int wv = tid >> 6;
    int lane15 = lane & 15;
    int kb = (lane >> 4) * 8;

    for (int idx = tid * 4; idx < NT * F; idx += TPB * 4) {
        int n = idx / F, k = idx - n * F;
        int gn = n0 + n;
        float4 v = (gn < N) ? *reinterpret_cast<const float4*>(xin + (size_t)gn * F + k)
                            : make_float4(0.f, 0.f, 0.f, 0.f);
        unsigned int lo = __builtin_bit_cast(unsigned int, pkrtz(v.x, v.y));
        unsigned int hi = __builtin_bit_cast(unsigned int, pkrtz(v.z, v.w));
        *reinterpret_cast<uint2*>(&xs[n][k]) = make_uint2(lo, hi);
    }

    f32x4v acc[4][CTW];
    #pragma unroll
    for (int t = 0; t < CTW; ++t) {
        int col = (wv * CTW + t) * 16 + lane15;
        float bv = (col < HC) ? bl[col] : br[col - HC];
        #pragma unroll
        for (int tr = 0; tr < 4; ++tr) acc[tr][t] = (f32x4v){bv, bv, bv, bv};
    }

    for (int kc = 0; kc < F; kc += KC) {
        __syncthreads();
        for (int idx = tid; idx < (KC / 2) * C4; idx += TPB) {
            int k2 = idx / C4;
            int c = (idx - k2 * C4) * 4;
            int k = kc + k2 * 2;
            float4 r0, r1;
            if (c < HC) {
                r0 = *reinterpret_cast<const float4*>(wl + (size_t)k * HC + c);
                r1 = *reinterpret_cast<const float4*>(wl + (size_t)(k + 1) * HC + c);
            } else {
                int cc = c - HC;
                r0 = *reinterpret_cast<const float4*>(wr + (size_t)k * HC + cc);
                r1 = *reinterpret_cast<const float4*>(wr + (size_t)(k + 1) * HC + cc);
            }
            int kk = k2 * 2;
            *reinterpret_cast<unsigned int*>(&wsT[c + 0][kk]) = __builtin_bit_cast(unsigned int, pkrtz(r0.x, r1.x));
            *reinterpret_cast<unsigned int*>(&wsT[c + 1][kk]) = __builtin_bit_cast(unsigned int, pkrtz(r0.y, r1.y));
            *reinterpret_cast<unsigned int*>(&wsT[c + 2][kk]) = __builtin_bit_cast(unsigned int, pkrtz(r0.z, r1.z));
            *reinterpret_cast<unsigned int*>(&wsT[c + 3][kk]) = __builtin_bit_cast(unsigned int, pkrtz(r0.w, r1.w));
        }
        __syncthreads();

        f16x8 a[4];
        #pragma unroll
        for (int tr = 0; tr < 4; ++tr)
            a[tr] = *reinterpret_cast<const f16x8*>(&xs[tr * 16 + lane15][kc + kb]);
        #pragma unroll
        for (int t = 0; t < CTW; ++t) {
            int col = (wv * CTW + t) * 16 + lane15;
            f16x8 bfr = *reinterpret_cast<const f16x8*>(&wsT[col][kb]);
            #pragma unroll
            for (int tr = 0; tr < 4; ++tr)
                acc[tr][t] = __builtin_amdgcn_mfma_f32_16x16x32_f16(a[tr], bfr, acc[tr][t], 0, 0, 0);
        }
    }

    #pragma unroll
    for (int t = 0; t < CTW; ++t) {
        int col = (wv * CTW + t) * 16 + lane15;
        bool isL = col < HC;
        __half* outp = isL ? xl16 : xr16;
        int c = isL ? col : col - HC;
        #pragma unroll
        for (int tr = 0; tr < 4; ++tr) {
            #pragma unroll
            for (int j = 0; j < 4; ++j) {
                int node = n0 + tr * 16 + (lane >> 4) * 4 + j;
                if (node < N) outp[(size_t)node * HC + c] = __float2half(acc[tr][t][j]);
            }
        }
    }
}

// ---------------- fused GATv2 attention + aggregation ----------------
// 8 channels/lane (R16-proven form): wave carries NPW=512/HC nodes.
template <int H, int C>
__global__ void k_fused(const int* __restrict__ rowptr,
                        const float4* __restrict__ cefs,
                        const __half* __restrict__ xl16, const __half* __restrict__ xr16,
                        const float* __restrict__ we, const float* __restrict__ att,
                        const float* __restrict__ cb, float* __restrict__ hout, int N) {
    constexpr int HC = H * C;
    constexpr int PAIRS = HC / 8;   // lanes per node (16 or 8)
    constexpr int NPW = 64 / PAIRS; // nodes per wave (4 or 8)
    constexpr int SPAN = C / 8;     // lanes per head (4 or 2)
    const _Float16* xl = reinterpret_cast<const _Float16*>(xl16);
    int wave = (blockIdx.x * blockDim.x + threadIdx.x) >> 6;
    int lane = threadIdx.x & 63;
    int g = lane / PAIRS;
    int p = lane % PAIRS;
    int node = wave * NPW + g;
    bool act = node < N;

    int o0 = 8 * p;
    hv8 xr8 = {};
    int b = 0, len = 0;
    if (act) {
        xr8 = *reinterpret_cast<const hv8*>(
            reinterpret_cast<const _Float16*>(xr16) + (size_t)node * HC + o0);
        b = rowptr[node];
        len = rowptr[node + 1] - b;
    }
    // we rows packed to f16
    hv8 wa8, wb8, wc8;
    float at[8];
    const float LOG2E = 1.44269504088896340736f;
    #pragma unroll
    for (int m = 0; m < 8; m += 2) {
        hv2 a2 = pkrtz(we[o0 + m], we[o0 + m + 1]);
        hv2 b2 = pkrtz(we[HC + o0 + m], we[HC + o0 + m + 1]);
        hv2 c2 = pkrtz(we[2 * HC + o0 + m], we[2 * HC + o0 + m + 1]);
        wa8[m] = a2[0]; wa8[m + 1] = a2[1];
        wb8[m] = b2[0]; wb8[m + 1] = b2[1];
        wc8[m] = c2[0]; wc8[m + 1] = c2[1];
        at[m] = att[o0 + m] * LOG2E;
        at[m + 1] = att[o0 + m + 1] * LOG2E;
    }
    const _Float16 K02 = (_Float16)0.2f;

    float m_run = -1e30f, den = 0.f;
    float acc[8];
    #pragma unroll
    for (int m = 0; m < 8; ++m) acc[m] = 0.f;

    int nk = (len + 3) >> 2;
    for (int kb = 0; kb < nk; ++kb) {
        int k0 = kb * 4;
        float L[4];
        hv8 xh[4];
        #pragma unroll
        for (int u = 0; u < 4; ++u) {
            int kk = k0 + u;
            bool v = kk < len;
            int s = b + (v ? kk : 0);
            float4 q = cefs[s];
            int src = __float_as_int(q.w);
            hv8 x8 = *reinterpret_cast<const hv8*>(xl + (size_t)src * HC + o0);
            _Float16 qx = (_Float16)q.x, qy = (_Float16)q.y, qz = (_Float16)q.z;
            hv8 t8 = x8 + (wa8 * qx + (wb8 * qy + (wc8 * qz + xr8)));
            hv8 lr = __builtin_elementwise_max(t8, t8 * K02);  // leaky-relu
            float partial = fmaf((float)lr[0], at[0], fmaf((float)lr[1], at[1],
                            fmaf((float)lr[2], at[2], fmaf((float)lr[3], at[3],
                            fmaf((float)lr[4], at[4], fmaf((float)lr[5], at[5],
                            fmaf((float)lr[6], at[6], (float)lr[7] * at[7])))))));
            partial = dpp_reduce<SPAN>(partial);   // VALU DPP butterfly
            L[u] = v ? partial : -1e30f;
            xh[u] = x8;
        }
        float Lm = fmaxf(fmaxf(L[0], L[1]), fmaxf(L[2], L[3]));
        float nm = fmaxf(m_run, Lm);
        float sc = __builtin_amdgcn_exp2f(m_run - nm);
        float p0 = __builtin_amdgcn_exp2f(L[0] - nm);
        float p1 = __builtin_amdgcn_exp2f(L[1] - nm);
        float p2 = __builtin_amdgcn_exp2f(L[2] - nm);
        float p3 = __builtin_amdgcn_exp2f(L[3] - nm);
        den = den * sc + ((p0 + p1) + (p2 + p3));
        #pragma unroll
        for (int m = 0; m < 8; ++m)
            acc[m] = fmaf(acc[m], sc, fmaf(p0, (float)xh[0][m], fmaf(p1, (float)xh[1][m],
                          fmaf(p2, (float)xh[2][m], p3 * (float)xh[3][m]))));
        m_run = nm;
    }

    if (act) {
        float inv = 1.0f / den;  // self-loop guarantees den > 0
        float* outp = hout + (size_t)node * HC + o0;
        float4 r0 = make_float4(fmaxf(acc[0] * inv + cb[o0 + 0], 0.f),
                                fmaxf(acc[1] * inv + cb[o0 + 1], 0.f),
                                fmaxf(acc[2] * inv + cb[o0 + 2], 0.f),
                                fmaxf(acc[3] * inv + cb[o0 + 3], 0.f));
        float4 r1 = make_float4(fmaxf(acc[4] * inv + cb[o0 + 4], 0.f),
                                fmaxf(acc[5] * inv + cb[o0 + 5], 0.f),
                                fmaxf(acc[6] * inv + cb[o0 + 6], 0.f),
                                fmaxf(acc[7] * inv + cb[o0 + 7], 0.f));
        *reinterpret_cast<float4*>(outp) = r0;
        *reinterpret_cast<float4*>(outp + 4) = r1;
    }
}

// ---------------- pooling + final linear ----------------
__global__ void k_pool(const float* __restrict__ h, const int* __restrict__ batch,
                       float* __restrict__ psum, int* __restrict__ pcnt, int N) {
    int o = threadIdx.x & 63;
    int j = threadIdx.x >> 6;
    int nb = blockIdx.x * 32;
    float acc = 0.f;
    int gcur = -1, cntacc = 0;
    for (int jj = j; jj < 32; jj += 4) {
        int node = nb + jj;
        if (node >= N) break;
        int g = batch[node];
        if (g != gcur) {
            if (gcur >= 0) {
                atomicAdd(&psum[gcur * 64 + o], acc);
                if (o == 0) atomicAdd(&pcnt[gcur], cntacc);
            }
            gcur = g; acc = 0.f; cntacc = 0;
        }
        acc += h[(size_t)node * 64 + o];
        ++cntacc;
    }
    if (gcur >= 0) {
        atomicAdd(&psum[gcur * 64 + o], acc);
        if (o == 0) atomicAdd(&pcnt[gcur], cntacc);
    }
}

__global__ void k_final(const float* __restrict__ psum, const int* __restrict__ pcnt,
                        const float* __restrict__ wlin, const float* __restrict__ blin,
                        float* __restrict__ out, int G) {
    int t = blockIdx.x * blockDim.x + threadIdx.x;
    if (t >= G * 32) return;
    int g = t / 32, j = t % 32;
    float acc = 0.f;
    for (int k = 0; k < 64; ++k) acc = fmaf(psum[g * 64 + k], wlin[k * 32 + j], acc);
    float inv = 1.0f / (float)max(pcnt[g], 1);
    out[t] = acc * inv + blin[j];
}

// ---------------- host ----------------

extern "C" void kernel_launch(void* const* d_in, const int* in_sizes, int n_in,
                              void* d_out, int out_size, void* d_ws, size_t ws_size,
                              hipStream_t stream) {
    const float* x = (const float*)d_in[0];
    const int* ei = (const int*)d_in[1];
    const float* ef = (const float*)d_in[2];
    const int* batch = (const int*)d_in[3];

    int N = in_sizes[0] / 5;
    int E = in_sizes[1] / 2;
    int G = out_size / 32;
    int Etot = E + N;
    const int* srcA = ei;
    const int* dstA = ei + E;

    char* w = (char*)d_ws;
    size_t off = 0;
    auto A = [&](size_t bytes) -> void* {
        void* p = w + off;
        off = (off + bytes + 255) & ~(size_t)255;
        return p;
    };
    // zero-init region: cnt0, psum, pcnt
    int* cnt0 = (int*)A((size_t)N * 4);
    float* psum = (float*)A((size_t)G * 64 * 4);
    int* pcnt = (int*)A((size_t)G * 4);
    size_t zbytes = off;
    int* rowptr = (int*)A((size_t)(N + 1) * 4);
    int* part = (int*)A((size_t)64 * 4);
    int* epos = (int*)A((size_t)E * 4);
    float4* cefs = (float4*)A((size_t)Etot * 16);
    __half* xl16 = (__half*)A((size_t)N * 128 * 2);
    __half* xr16 = (__half*)A((size_t)N * 128 * 2);
    float* h0 = (float*)A((size_t)N * 128 * 4);
    float* h1 = (float*)A((size_t)N * 128 * 4);

    (void)hipMemsetAsync(d_ws, 0, zbytes, stream);

    dim3 B(TPB);
    int nblkN = (N + TPB - 1) / TPB;
    int nblkE = (E + TPB - 1) / TPB;
    k_count2<<<nblkE, B, 0, stream>>>(dstA, cnt0, epos, E);

    int ept = (N + 64 * TPB - 1) / (64 * TPB);
    if (ept < 4) ept = 4;
    int nb = (N + ept * TPB - 1) / (ept * TPB);
    k_scan_part<<<nb, B, 0, stream>>>(cnt0, part, N, ept);
    k_scan_top<<<1, 64, 0, stream>>>(part, rowptr, nb, N);
    k_scan_fin<<<nb, B, 0, stream>>>(cnt0, part, rowptr, N, ept);

    k_fill2<<<nblkE, B, 0, stream>>>(srcA, dstA, epos, ef, rowptr, cefs, E);
    k_selfloop<<<nblkN, B, 0, stream>>>(rowptr, cnt0, cefs, N);

    float* houts[4] = {h0, h1, h0, h1};

    int nblk = (N + 31) / 32;
    int nblk64 = (N + 63) / 64;
    const float* hin = x;
    for (int l = 0; l < 4; ++l) {
        const float* wl  = (const float*)d_in[4 + l * 7 + 0];
        const float* bl  = (const float*)d_in[4 + l * 7 + 1];
        const float* wr  = (const float*)d_in[4 + l * 7 + 2];
        const float* br  = (const float*)d_in[4 + l * 7 + 3];
        const float* we  = (const float*)d_in[4 + l * 7 + 4];
        const float* att = (const float*)d_in[4 + l * 7 + 5];
        const float* cb  = (const float*)d_in[4 + l * 7 + 6];
        int H = (l == 3) ? 2 : 4;
        int C = (l == 0) ? 16 : 32;
        int HC = H * C;

        if (l == 0)      k_lin_s<5, 64>      <<<nblk, B, 0, stream>>>(hin, wl, bl, wr, br, xl16, xr16, N);
        else if (l == 1) k_lin_mfma<64, 128> <<<nblk64, B, 0, stream>>>(hin, wl, bl, wr, br, xl16, xr16, N);
        else if (l == 2) k_lin_mfma<128, 128><<<nblk64, B, 0, stream>>>(hin, wl, bl, wr, br, xl16, xr16, N);
        else             k_lin_mfma<128, 64> <<<nblk64, B, 0, stream>>>(hin, wl, bl, wr, br, xl16, xr16, N);

        int npw = 512 / HC;  // nodes per wave at 8 channels/lane
        long long waves = ((long long)N + npw - 1) / npw;
        int blocks = (int)((waves + 3) / 4);
        if (H == 4 && C == 16)
            k_fused<4, 16><<<blocks, B, 0, stream>>>(rowptr, cefs, xl16, xr16,
                                                     we, att, cb, houts[l], N);
        else if (H == 4 && C == 32)
            k_fused<4, 32><<<blocks, B, 0, stream>>>(rowptr, cefs, xl16, xr16,
                                                     we, att, cb, houts[l], N);
        else
            k_fused<2, 32><<<blocks, B, 0, stream>>>(rowptr, cefs, xl16, xr16,
                                                     we, att, cb, houts[l], N);
        hin = houts[l];
    }

    k_pool<<<(N + 31) / 32, B, 0, stream>>>(hin, batch, psum, pcnt, N);
    k_final<<<(G * 32 + TPB - 1) / TPB, B, 0, stream>>>(psum, pcnt,
                                                        (const float*)d_in[32],
                                                        (const float*)d_in[33],
                                                        (float*)d_out, G);
}

// Round 22
// 358.956 us; speedup vs baseline: 1.2840x; 1.0006x over previous
//
#include <hip/hip_runtime.h>
#include <hip/hip_fp16.h>

#define TPB 256

typedef _Float16 hv2 __attribute__((ext_vector_type(2)));
typedef _Float16 hv8 __attribute__((ext_vector_type(8)));
typedef _Float16 f16x8 __attribute__((ext_vector_type(8)));
typedef float f32x4v __attribute__((ext_vector_type(4)));

static __device__ __forceinline__ hv2 pkrtz(float a, float b) {
    auto t = __builtin_amdgcn_cvt_pkrtz(a, b);
    return __builtin_bit_cast(hv2, t);
}

template <int CTRL>
static __device__ __forceinline__ float dpp_add(float x) {
    int xi = __builtin_bit_cast(int, x);
    int yi = __builtin_amdgcn_update_dpp(0, xi, CTRL, 0xf, 0xf, true);
    return x + __builtin_bit_cast(float, yi);
}

// butterfly sum over SPAN lanes (SPAN = 2,4,8,16; within a DPP row of 16)
template <int SPAN>
static __device__ __forceinline__ float dpp_reduce(float x) {
    x = dpp_add<0xB1>(x);                              // quad_perm xor1
    if constexpr (SPAN >= 4)  x = dpp_add<0x4E>(x);    // quad_perm xor2
    if constexpr (SPAN >= 8)  x = dpp_add<0x141>(x);   // row_half_mirror == ^7
    if constexpr (SPAN >= 16) x = dpp_add<0x140>(x);   // row_mirror == ^15
    return x;
}

// ---------------- CSR build ----------------

// count + within-row position in one pass (epos write is coalesced)
__global__ void k_count2(const int* __restrict__ dstA, int* __restrict__ cnt,
                         int* __restrict__ epos, int E) {
    int e = blockIdx.x * blockDim.x + threadIdx.x;
    if (e >= E) return;
    epos[e] = atomicAdd(&cnt[dstA[e]], 1);
}

// ---- 3-phase exclusive scan of (cnt[i]+1) ----
__global__ void k_scan_part(const int* __restrict__ cnt, int* __restrict__ part,
                            int N, int ept) {
    __shared__ int sm[TPB];
    int tid = threadIdx.x;
    int beg = (blockIdx.x * TPB + tid) * ept;
    int s = 0;
    for (int u = 0; u < ept; ++u) {
        int i = beg + u;
        if (i < N) s += cnt[i] + 1;
    }
    sm[tid] = s;
    __syncthreads();
    for (int st = TPB / 2; st; st >>= 1) {
        if (tid < st) sm[tid] += sm[tid + st];
        __syncthreads();
    }
    if (tid == 0) part[blockIdx.x] = sm[0];
}

__global__ void k_scan_top(int* __restrict__ part, int* __restrict__ rowptr,
                           int nb, int N) {
    int lane = threadIdx.x & 63;
    int orig = (lane < nb) ? part[lane] : 0;
    int v = orig;
    #pragma unroll
    for (int ofs = 1; ofs < 64; ofs <<= 1) {
        int t = __shfl_up(v, ofs);
        if (lane >= ofs) v += t;
    }
    if (lane < nb) part[lane] = v - orig;
    if (lane == 63) rowptr[N] = v;
}

__global__ void k_scan_fin(const int* __restrict__ cnt, const int* __restrict__ part,
                           int* __restrict__ rowptr, int N, int ept) {
    __shared__ int wsum[TPB / 64];
    int tid = threadIdx.x;
    int lane = tid & 63, wid = tid >> 6;
    int beg = (blockIdx.x * TPB + tid) * ept;
    int s = 0;
    for (int u = 0; u < ept; ++u) {
        int i = beg + u;
        if (i < N) s += cnt[i] + 1;
    }
    int v = s;
    #pragma unroll
    for (int ofs = 1; ofs < 64; ofs <<= 1) {
        int t = __shfl_up(v, ofs);
        if (lane >= ofs) v += t;
    }
    if (lane == 63) wsum[wid] = v;
    __syncthreads();
    int woff = 0;
    for (int k = 0; k < wid; ++k) woff += wsum[k];
    int acc = (v - s) + woff + part[blockIdx.x];
    for (int u = 0; u < ept; ++u) {
        int i = beg + u;
        if (i < N) { rowptr[i] = acc; acc += cnt[i] + 1; }
    }
}

// edge scatter, 4 edges/thread for MLP: slot = rowptr[dst] + epos (no atomic)
__global__ void k_fill2(const int* __restrict__ srcA, const int* __restrict__ dstA,
                        const int* __restrict__ epos, const float* __restrict__ ef,
                        const int* __restrict__ rowptr, float4* __restrict__ cefs, int E) {
    int e0 = (blockIdx.x * blockDim.x + threadIdx.x) * 4;
    int d[4], p[4], sa[4];
    float f0[4], f1[4], f2[4];
    #pragma unroll
    for (int u = 0; u < 4; ++u) {
        int e = e0 + u;
        if (e >= E) break;
        d[u] = dstA[e];
        p[u] = epos[e];
        sa[u] = srcA[e];
        f0[u] = ef[e * 3 + 0];
        f1[u] = ef[e * 3 + 1];
        f2[u] = ef[e * 3 + 2];
    }
    #pragma unroll
    for (int u = 0; u < 4; ++u) {
        int e = e0 + u;
        if (e >= E) break;
        int slot = rowptr[d[u]] + p[u];
        cefs[slot] = make_float4(f0[u], f1[u], f2[u], __int_as_float(sa[u]));
    }
}

// self-loop mean: 4 lanes per node (aligned quad), DPP quad-reduce
__global__ void k_selfloop(const int* __restrict__ rowptr, const int* __restrict__ cnt,
                           float4* __restrict__ cefs, int N) {
    int t = blockIdx.x * blockDim.x + threadIdx.x;
    int node = t >> 2;
    int s4 = t & 3;
    if (node >= N) return;
    int b = rowptr[node];
    int c = cnt[node];
    float s0 = 0.f, s1 = 0.f, s2 = 0.f;
    for (int s = b + s4; s < b + c; s += 4) {
        float4 q = cefs[s];
        s0 += q.x; s1 += q.y; s2 += q.z;
    }
    s0 = dpp_reduce<4>(s0);
    s1 = dpp_reduce<4>(s1);
    s2 = dpp_reduce<4>(s2);
    if (s4 == 0) {
        float inv = 1.0f / (float)max(c, 1);
        cefs[b + c] = make_float4(s0 * inv, s1 * inv, s2 * inv, __int_as_float(node));
    }
}

// ---------------- layer-0 linear (F=5): simple register-tiled ----------------
template <int F, int HC>
__global__ void k_lin_s(const float* __restrict__ xin,
                        const float* __restrict__ wl, const float* __restrict__ bl,
                        const float* __restrict__ wr, const float* __restrict__ br,
                        __half* __restrict__ xl16, __half* __restrict__ xr16, int N) {
    constexpr int OPT = HC / 16;
    __shared__ float xs[32][F + 1];
    int n0 = blockIdx.x * 32;
    int tid = threadIdx.x;

    for (int idx = tid; idx < 32 * F; idx += TPB) {
        int n = idx / F, k = idx - n * F;
        int gn = n0 + n;
        xs[n][k] = (gn < N) ? xin[(size_t)gn * F + k] : 0.f;
    }
    __syncthreads();

    int og = tid & 31;
    int ng = tid >> 5;
    int o0 = og * OPT;
    bool isL = o0 < HC;
    int col = isL ? o0 : o0 - HC;
    const float* wp = isL ? wl : wr;
    const float* bp = isL ? bl : br;
    __half* outp = isL ? xl16 : xr16;

    float acc[4][OPT];
    #pragma unroll
    for (int j = 0; j < 4; ++j)
        #pragma unroll
        for (int m = 0; m < OPT; ++m) acc[j][m] = 0.f;

    #pragma unroll
    for (int k = 0; k < F; ++k) {
        float wv[OPT];
        #pragma unroll
        for (int m = 0; m < OPT; m += 4)
            *reinterpret_cast<float4*>(&wv[m]) =
                *reinterpret_cast<const float4*>(wp + (size_t)k * HC + col + m);
        #pragma unroll
        for (int j = 0; j < 4; ++j) {
            float xv = xs[ng * 4 + j][k];
            #pragma unroll
            for (int m = 0; m < OPT; ++m) acc[j][m] = fmaf(xv, wv[m], acc[j][m]);
        }
    }

    float bias[OPT];
    #pragma unroll
    for (int m = 0; m < OPT; ++m) bias[m] = bp[col + m];

    #pragma unroll
    for (int j = 0; j < 4; ++j) {
        int node = n0 + ng * 4 + j;
        if (node >= N) continue;
        #pragma unroll
        for (int m = 0; m < OPT; m += 2) {
            __half2 hv = __half2(__float2half(acc[j][m] + bias[m]),
                                 __float2half(acc[j][m + 1] + bias[m + 1]));
            *reinterpret_cast<__half2*>(outp + (size_t)node * HC + col + m) = hv;
        }
    }
}

// ---------------- big linear layers: MFMA fp16 GEMM ----------------
template <int F, int HC>
__global__ void k_lin_mfma(const float* __restrict__ xin,
                           const float* __restrict__ wl, const float* __restrict__ bl,
                           const float* __restrict__ wr, const float* __restrict__ br,
                           __half* __restrict__ xl16, __half* __restrict__ xr16, int N) {
    constexpr int W2 = 2 * HC;
    constexpr int NT = 64;
    constexpr int KC = 32;
    constexpr int CT = W2 / 16;
    constexpr int CTW = CT / 4;
    constexpr int C4 = W2 / 4;
    __shared__ _Float16 xs[NT][F + 8];
    __shared__ _Float16 wsT[W2][KC + 8];

    int n0 = blockIdx.x * NT;
    int tid = threadIdx.x;
    int lane = tid & 63;
    int wv = tid >> 6;
    int lane15 = lane & 15;
    int kb = (lane >> 4) * 8;

    for (int idx = tid * 4; idx < NT * F; idx += TPB * 4) {
        int n = idx / F, k = idx - n * F;
        int gn = n0 + n;
        float4 v = (gn < N) ? *reinterpret_cast<const float4*>(xin + (size_t)gn * F + k)
                            : make_float4(0.f, 0.f, 0.f, 0.f);
        unsigned int lo = __builtin_bit_cast(unsigned int, pkrtz(v.x, v.y));
        unsigned int hi = __builtin_bit_cast(unsigned int, pkrtz(v.z, v.w));
        *reinterpret_cast<uint2*>(&xs[n][k]) = make_uint2(lo, hi);
    }

    f32x4v acc[4][CTW];
    #pragma unroll
    for (int t = 0; t < CTW; ++t) {
        int col = (wv * CTW + t) * 16 + lane15;
        float bv = (col < HC) ? bl[col] : br[col - HC];
        #pragma unroll
        for (int tr = 0; tr < 4; ++tr) acc[tr][t] = (f32x4v){bv, bv, bv, bv};
    }

    for (int kc = 0; kc < F; kc += KC) {
        __syncthreads();
        for (int idx = tid; idx < (KC / 2) * C4; idx += TPB) {
            int k2 = idx / C4;
            int c = (idx - k2 * C4) * 4;
            int k = kc + k2 * 2;
            float4 r0, r1;
            if (c < HC) {
                r0 = *reinterpret_cast<const float4*>(wl + (size_t)k * HC + c);
                r1 = *reinterpret_cast<const float4*>(wl + (size_t)(k + 1) * HC + c);
            } else {
                int cc = c - HC;
                r0 = *reinterpret_cast<const float4*>(wr + (size_t)k * HC + cc);
                r1 = *reinterpret_cast<const float4*>(wr + (size_t)(k + 1) * HC + cc);
            }
            int kk = k2 * 2;
            *reinterpret_cast<unsigned int*>(&wsT[c + 0][kk]) = __builtin_bit_cast(unsigned int, pkrtz(r0.x, r1.x));
            *reinterpret_cast<unsigned int*>(&wsT[c + 1][kk]) = __builtin_bit_cast(unsigned int, pkrtz(r0.y, r1.y));
            *reinterpret_cast<unsigned int*>(&wsT[c + 2][kk]) = __builtin_bit_cast(unsigned int, pkrtz(r0.z, r1.z));
            *reinterpret_cast<unsigned int*>(&wsT[c + 3][kk]) = __builtin_bit_cast(unsigned int, pkrtz(r0.w, r1.w));
        }
        __syncthreads();

        f16x8 a[4];
        #pragma unroll
        for (int tr = 0; tr < 4; ++tr)
            a[tr] = *reinterpret_cast<const f16x8*>(&xs[tr * 16 + lane15][kc + kb]);
        #pragma unroll
        for (int t = 0; t < CTW; ++t) {
            int col = (wv * CTW + t) * 16 + lane15;
            f16x8 bfr = *reinterpret_cast<const f16x8*>(&wsT[col][kb]);
            #pragma unroll
            for (int tr = 0; tr < 4; ++tr)
                acc[tr][t] = __builtin_amdgcn_mfma_f32_16x16x32_f16(a[tr], bfr, acc[tr][t], 0, 0, 0);
        }
    }

    #pragma unroll
    for (int t = 0; t < CTW; ++t) {
        int col = (wv * CTW + t) * 16 + lane15;
        bool isL = col < HC;
        __half* outp = isL ? xl16 : xr16;
        int c = isL ? col : col - HC;
        #pragma unroll
        for (int tr = 0; tr < 4; ++tr) {
            #pragma unroll
            for (int j = 0; j < 4; ++j) {
                int node = n0 + tr * 16 + (lane >> 4) * 4 + j;
                if (node < N) outp[(size_t)node * HC + c] = __float2half(acc[tr][t][j]);
            }
        }
    }
}

// ---------------- fused GATv2 attention + aggregation ----------------
// 8 channels/lane (R16-proven form) + setprio around the merge phase.
template <int H, int C>
__global__ void k_fused(const int* __restrict__ rowptr,
                        const float4* __restrict__ cefs,
                        const __half* __restrict__ xl16, const __half* __restrict__ xr16,
                        const float* __restrict__ we, const float* __restrict__ att,
                        const float* __restrict__ cb, float* __restrict__ hout, int N) {
    constexpr int HC = H * C;
    constexpr int PAIRS = HC / 8;   // lanes per node (16 or 8)
    constexpr int NPW = 64 / PAIRS; // nodes per wave (4 or 8)
    constexpr int SPAN = C / 8;     // lanes per head (4 or 2)
    const _Float16* xl = reinterpret_cast<const _Float16*>(xl16);
    int wave = (blockIdx.x * blockDim.x + threadIdx.x) >> 6;
    int lane = threadIdx.x & 63;
    int g = lane / PAIRS;
    int p = lane % PAIRS;
    int node = wave * NPW + g;
    bool act = node < N;

    int o0 = 8 * p;
    hv8 xr8 = {};
    int b = 0, len = 0;
    if (act) {
        xr8 = *reinterpret_cast<const hv8*>(
            reinterpret_cast<const _Float16*>(xr16) + (size_t)node * HC + o0);
        b = rowptr[node];
        len = rowptr[node + 1] - b;
    }
    // we rows packed to f16
    hv8 wa8, wb8, wc8;
    float at[8];
    const float LOG2E = 1.44269504088896340736f;
    #pragma unroll
    for (int m = 0; m < 8; m += 2) {
        hv2 a2 = pkrtz(we[o0 + m], we[o0 + m + 1]);
        hv2 b2 = pkrtz(we[HC + o0 + m], we[HC + o0 + m + 1]);
        hv2 c2 = pkrtz(we[2 * HC + o0 + m], we[2 * HC + o0 + m + 1]);
        wa8[m] = a2[0]; wa8[m + 1] = a2[1];
        wb8[m] = b2[0]; wb8[m + 1] = b2[1];
        wc8[m] = c2[0]; wc8[m + 1] = c2[1];
        at[m] = att[o0 + m] * LOG2E;
        at[m + 1] = att[o0 + m + 1] * LOG2E;
    }
    const _Float16 K02 = (_Float16)0.2f;

    float m_run = -1e30f, den = 0.f;
    float acc[8];
    #pragma unroll
    for (int m = 0; m < 8; ++m) acc[m] = 0.f;

    int nk = (len + 3) >> 2;
    for (int kb = 0; kb < nk; ++kb) {
        int k0 = kb * 4;
        float L[4];
        hv8 xh[4];
        #pragma unroll
        for (int u = 0; u < 4; ++u) {
            int kk = k0 + u;
            bool v = kk < len;
            int s = b + (v ? kk : 0);
            float4 q = cefs[s];
            int src = __float_as_int(q.w);
            hv8 x8 = *reinterpret_cast<const hv8*>(xl + (size_t)src * HC + o0);
            _Float16 qx = (_Float16)q.x, qy = (_Float16)q.y, qz = (_Float16)q.z;
            hv8 t8 = x8 + (wa8 * qx + (wb8 * qy + (wc8 * qz + xr8)));
            hv8 lr = __builtin_elementwise_max(t8, t8 * K02);  // leaky-relu
            float partial = fmaf((float)lr[0], at[0], fmaf((float)lr[1], at[1],
                            fmaf((float)lr[2], at[2], fmaf((float)lr[3], at[3],
                            fmaf((float)lr[4], at[4], fmaf((float)lr[5], at[5],
                            fmaf((float)lr[6], at[6], (float)lr[7] * at[7])))))));
            partial = dpp_reduce<SPAN>(partial);   // VALU DPP butterfly
            L[u] = v ? partial : -1e30f;
            xh[u] = x8;
        }
        __builtin_amdgcn_s_setprio(1);
        float Lm = fmaxf(fmaxf(L[0], L[1]), fmaxf(L[2], L[3]));
        float nm = fmaxf(m_run, Lm);
        float sc = __builtin_amdgcn_exp2f(m_run - nm);
        float p0 = __builtin_amdgcn_exp2f(L[0] - nm);
        float p1 = __builtin_amdgcn_exp2f(L[1] - nm);
        float p2 = __builtin_amdgcn_exp2f(L[2] - nm);
        float p3 = __builtin_amdgcn_exp2f(L[3] - nm);
        den = den * sc + ((p0 + p1) + (p2 + p3));
        #pragma unroll
        for (int m = 0; m < 8; ++m)
            acc[m] = fmaf(acc[m], sc, fmaf(p0, (float)xh[0][m], fmaf(p1, (float)xh[1][m],
                          fmaf(p2, (float)xh[2][m], p3 * (float)xh[3][m]))));
        m_run = nm;
        __builtin_amdgcn_s_setprio(0);
    }

    if (act) {
        float inv = 1.0f / den;  // self-loop guarantees den > 0
        float* outp = hout + (size_t)node * HC + o0;
        float4 r0 = make_float4(fmaxf(acc[0] * inv + cb[o0 + 0], 0.f),
                                fmaxf(acc[1] * inv + cb[o0 + 1], 0.f),
                                fmaxf(acc[2] * inv + cb[o0 + 2], 0.f),
                                fmaxf(acc[3] * inv + cb[o0 + 3], 0.f));
        float4 r1 = make_float4(fmaxf(acc[4] * inv + cb[o0 + 4], 0.f),
                                fmaxf(acc[5] * inv + cb[o0 + 5], 0.f),
                                fmaxf(acc[6] * inv + cb[o0 + 6], 0.f),
                                fmaxf(acc[7] * inv + cb[o0 + 7], 0.f));
        *reinterpret_cast<float4*>(outp) = r0;
        *reinterpret_cast<float4*>(outp + 4) = r1;
    }
}

// ---------------- pooling + final linear ----------------
__global__ void k_pool(const float* __restrict__ h, const int* __restrict__ batch,
                       float* __restrict__ psum, int* __restrict__ pcnt, int N) {
    int o = threadIdx.x & 63;
    int j = threadIdx.x >> 6;
    int nb = blockIdx.x * 32;
    float acc = 0.f;
    int gcur = -1, cntacc = 0;
    for (int jj = j; jj < 32; jj += 4) {
        int node = nb + jj;
        if (node >= N) break;
        int g = batch[node];
        if (g != gcur) {
            if (gcur >= 0) {
                atomicAdd(&psum[gcur * 64 + o], acc);
                if (o == 0) atomicAdd(&pcnt[gcur], cntacc);
            }
            gcur = g; acc = 0.f; cntacc = 0;
        }
        acc += h[(size_t)node * 64 + o];
        ++cntacc;
    }
    if (gcur >= 0) {
        atomicAdd(&psum[gcur * 64 + o], acc);
        if (o == 0) atomicAdd(&pcnt[gcur], cntacc);
    }
}

__global__ void k_final(const float* __restrict__ psum, const int* __restrict__ pcnt,
                        const float* __restrict__ wlin, const float* __restrict__ blin,
                        float* __restrict__ out, int G) {
    int t = blockIdx.x * blockDim.x + threadIdx.x;
    if (t >= G * 32) return;
    int g = t / 32, j = t % 32;
    float acc = 0.f;
    for (int k = 0; k < 64; ++k) acc = fmaf(psum[g * 64 + k], wlin[k * 32 + j], acc);
    float inv = 1.0f / (float)max(pcnt[g], 1);
    out[t] = acc * inv + blin[j];
}

// ---------------- host ----------------

extern "C" void kernel_launch(void* const* d_in, const int* in_sizes, int n_in,
                              void* d_out, int out_size, void* d_ws, size_t ws_size,
                              hipStream_t stream) {
    const float* x = (const float*)d_in[0];
    const int* ei = (const int*)d_in[1];
    const float* ef = (const float*)d_in[2];
    const int* batch = (const int*)d_in[3];

    int N = in_sizes[0] / 5;
    int E = in_sizes[1] / 2;
    int G = out_size / 32;
    int Etot = E + N;
    const int* srcA = ei;
    const int* dstA = ei + E;

    char* w = (char*)d_ws;
    size_t off = 0;
    auto A = [&](size_t bytes) -> void* {
        void* p = w + off;
        off = (off + bytes + 255) & ~(size_t)255;
        return p;
    };
    // zero-init region: cnt0, psum, pcnt
    int* cnt0 = (int*)A((size_t)N * 4);
    float* psum = (float*)A((size_t)G * 64 * 4);
    int* pcnt = (int*)A((size_t)G * 4);
    size_t zbytes = off;
    int* rowptr = (int*)A((size_t)(N + 1) * 4);
    int* part = (int*)A((size_t)64 * 4);
    int* epos = (int*)A((size_t)E * 4);
    float4* cefs = (float4*)A((size_t)Etot * 16);
    __half* xl16 = (__half*)A((size_t)N * 128 * 2);
    __half* xr16 = (__half*)A((size_t)N * 128 * 2);
    float* h0 = (float*)A((size_t)N * 128 * 4);
    float* h1 = (float*)A((size_t)N * 128 * 4);

    (void)hipMemsetAsync(d_ws, 0, zbytes, stream);

    dim3 B(TPB);
    int nblkE = (E + TPB - 1) / TPB;
    k_count2<<<nblkE, B, 0, stream>>>(dstA, cnt0, epos, E);

    int ept = (N + 64 * TPB - 1) / (64 * TPB);
    if (ept < 4) ept = 4;
    int nb = (N + ept * TPB - 1) / (ept * TPB);
    k_scan_part<<<nb, B, 0, stream>>>(cnt0, part, N, ept);
    k_scan_top<<<1, 64, 0, stream>>>(part, rowptr, nb, N);
    k_scan_fin<<<nb, B, 0, stream>>>(cnt0, part, rowptr, N, ept);

    int nblkE4 = ((E + 3) / 4 + TPB - 1) / TPB;
    k_fill2<<<nblkE4, B, 0, stream>>>(srcA, dstA, epos, ef, rowptr, cefs, E);
    int nblkN4 = ((long long)N * 4 + TPB - 1) / TPB;
    k_selfloop<<<nblkN4, B, 0, stream>>>(rowptr, cnt0, cefs, N);

    float* houts[4] = {h0, h1, h0, h1};

    int nblk = (N + 31) / 32;
    int nblk64 = (N + 63) / 64;
    const float* hin = x;
    for (int l = 0; l < 4; ++l) {
        const float* wl  = (const float*)d_in[4 + l * 7 + 0];
        const float* bl  = (const float*)d_in[4 + l * 7 + 1];
        const float* wr  = (const float*)d_in[4 + l * 7 + 2];
        const float* br  = (const float*)d_in[4 + l * 7 + 3];
        const float* we  = (const float*)d_in[4 + l * 7 + 4];
        const float* att = (const float*)d_in[4 + l * 7 + 5];
        const float* cb  = (const float*)d_in[4 + l * 7 + 6];
        int H = (l == 3) ? 2 : 4;
        int C = (l == 0) ? 16 : 32;
        int HC = H * C;

        if (l == 0)      k_lin_s<5, 64>      <<<nblk, B, 0, stream>>>(hin, wl, bl, wr, br, xl16, xr16, N);
        else if (l == 1) k_lin_mfma<64, 128> <<<nblk64, B, 0, stream>>>(hin, wl, bl, wr, br, xl16, xr16, N);
        else if (l == 2) k_lin_mfma<128, 128><<<nblk64, B, 0, stream>>>(hin, wl, bl, wr, br, xl16, xr16, N);
        else             k_lin_mfma<128, 64> <<<nblk64, B, 0, stream>>>(hin, wl, bl, wr, br, xl16, xr16, N);

        int npw = 512 / HC;  // nodes per wave at 8 channels/lane
        long long waves = ((long long)N + npw - 1) / npw;
        int blocks = (int)((waves + 3) / 4);
        if (H == 4 && C == 16)
            k_fused<4, 16><<<blocks, B, 0, stream>>>(rowptr, cefs, xl16, xr16,
                                                     we, att, cb, houts[l], N);
        else if (H == 4 && C == 32)
            k_fused<4, 32><<<blocks, B, 0, stream>>>(rowptr, cefs, xl16, xr16,
                                                     we, att, cb, houts[l], N);
        else
            k_fused<2, 32><<<blocks, B, 0, stream>>>(rowptr, cefs, xl16, xr16,
                                                     we, att, cb, houts[l], N);
        hin = houts[l];
    }

    k_pool<<<(N + 31) / 32, B, 0, stream>>>(hin, batch, psum, pcnt, N);
    k_final<<<(G * 32 + TPB - 1) / TPB, B, 0, stream>>>(psum, pcnt,
                                                        (const float*)d_in[32],
                                                        (const float*)d_in[33],
                                                        (float*)d_out, G);
}